// Round 14
// baseline (149.381 us; speedup 1.0000x reference)
//
#include <hip/hip_runtime.h>

// GNN encoder: input MLP + LN, 2x SAGEConv(mean) + ReLU + residual + LN, classifier MLP.
// Round 14 (base = round 13): DAG re-binning to hide k_fill.
//   k_zero -> k_pre_deg (ALL weight transpose + degree/rank rider)
//   -> scan_block -> scan_add -> k_fill_mlp (MLP blocks + fill-scatter rider)
//   -> gather8 -> sage0 -> gather8 -> sage_cls
// fp8 gather path and all kernel bodies unchanged from round 13.

namespace {

constexpr int NN = 50000;
constexpr int EE = 640000;
constexpr int HH = 128;
constexpr int CC = 40;
constexpr int SCAN_NB = (NN + 255) / 256;  // 196
constexpr int MG = (NN + 127) / 128;       // 391 (mlp blocks)
constexpr int FILLB = (EE + 255) / 256;    // 2500 (fill / degree blocks)
constexpr int WTB = (7 * 16384 + CC * 128 + 255) / 256;  // 468 (all wt slots)

typedef unsigned short u16;
typedef __attribute__((ext_vector_type(8))) short s16x8;
typedef __attribute__((ext_vector_type(8))) unsigned short u16x8;
typedef __attribute__((ext_vector_type(4))) float f32x4;
typedef __attribute__((ext_vector_type(2))) float f32x2;

__device__ __forceinline__ float b2f(u16 h) {
  unsigned int u = ((unsigned int)h) << 16;
  return __builtin_bit_cast(float, u);
}
__device__ __forceinline__ u16 f2b(float f) {
  unsigned int u = __builtin_bit_cast(unsigned int, f);
  u += 0x7FFFu + ((u >> 16) & 1u);
  return (u16)(u >> 16);
}

// pack 8 floats -> 8 fp8 e4m3 bytes
__device__ __forceinline__ uint2 pack_fp8(const float* v) {
  int w0 = 0, w1 = 0;
  w0 = __builtin_amdgcn_cvt_pk_fp8_f32(v[0], v[1], w0, false);
  w0 = __builtin_amdgcn_cvt_pk_fp8_f32(v[2], v[3], w0, true);
  w1 = __builtin_amdgcn_cvt_pk_fp8_f32(v[4], v[5], w1, false);
  w1 = __builtin_amdgcn_cvt_pk_fp8_f32(v[6], v[7], w1, true);
  return make_uint2((unsigned)w0, (unsigned)w1);
}
__device__ __forceinline__ void acc_fp8(float* a, uint2 p) {
  const f32x2 f0 = __builtin_amdgcn_cvt_pk_f32_fp8((int)p.x, false);
  const f32x2 f1 = __builtin_amdgcn_cvt_pk_f32_fp8((int)p.x, true);
  const f32x2 f2 = __builtin_amdgcn_cvt_pk_f32_fp8((int)p.y, false);
  const f32x2 f3 = __builtin_amdgcn_cvt_pk_f32_fp8((int)p.y, true);
  a[0] += f0.x; a[1] += f0.y; a[2] += f1.x; a[3] += f1.y;
  a[4] += f2.x; a[5] += f2.y; a[6] += f3.x; a[7] += f3.y;
}

// ---- swizzled LDS tile: row n, 16B-granule k0; slot = k0 ^ (n&15) ----
__device__ __forceinline__ s16x8 ldsw(const u16* base, int n, int k0) {
  return *reinterpret_cast<const s16x8*>(base + n * 128 + (((k0 ^ n) & 15) << 3));
}
__device__ __forceinline__ void stsw(u16* base, int r, int c, u16 v) {
  base[r * 128 + ((((c >> 3) ^ r) & 15) << 3) + (c & 7)] = v;
}
template <int NGRAN>
__device__ __forceinline__ void stage(const u16* __restrict__ src, u16* dst, int tid) {
#pragma unroll
  for (int i = 0; i < (NGRAN + 255) / 256; ++i) {
    const int gi = i * 256 + tid;
    if ((NGRAN & 255) == 0 || gi < NGRAN) {
      const int n = gi >> 4, k0 = gi & 15;
      const u16x8 v = *reinterpret_cast<const u16x8*>(src + gi * 8);
      *reinterpret_cast<u16x8*>(dst + n * 128 + (((k0 ^ n) & 15) << 3)) = v;
    }
  }
}

// ---------------- zero cnt ----------------
__global__ void k_zero(int* __restrict__ p) {
  const int i = blockIdx.x * 256 + threadIdx.x;
  if (i < NN) p[i] = 0;
}

// ---------------- weight transpose (all 8 slots) + degree/rank rider ----------------
__global__ void k_pre_deg(const float* __restrict__ pw1, const float* __restrict__ pw2,
                          const float* __restrict__ swl, const float* __restrict__ swr,
                          const float* __restrict__ cw1, const float* __restrict__ cw2,
                          u16* __restrict__ wt,
                          const int* __restrict__ ei, int* __restrict__ cnt,
                          int* __restrict__ rank) {
  if (blockIdx.x >= WTB) {
    const int e = (blockIdx.x - WTB) * 256 + threadIdx.x;
    if (e < EE) rank[e] = atomicAdd(&cnt[ei[EE + e]], 1);
    return;
  }
  int flat = blockIdx.x * 256 + threadIdx.x;
  const int SEVEN = 7 * 16384;
  if (flat < SEVEN) {
    int id = flat >> 14;
    int off = flat & 16383;
    int n = off >> 7, k = off & 127;
    const float* s;
    switch (id) {
      case 0: s = pw1; break;
      case 1: s = pw2; break;
      case 2: s = swl; break;
      case 3: s = swl + 16384; break;
      case 4: s = swr; break;
      case 5: s = swr + 16384; break;
      default: s = cw1; break;
    }
    wt[(size_t)id * 16384 + n * 128 + k] = f2b(s[k * 128 + n]);
  } else {
    int off = flat - SEVEN;
    if (off < CC * 128) {
      int n = off >> 7, k = off & 127;
      wt[(size_t)7 * 16384 + n * 128 + k] = f2b(cw2[k * CC + n]);
    }
  }
}

// ---------------- CSR scan ----------------
__global__ void k_scan_block(const int* __restrict__ cnt, int* __restrict__ rowptr,
                             int* __restrict__ bsum, float* __restrict__ inv) {
  __shared__ int s[256];
  const int t = threadIdx.x;
  const int i = blockIdx.x * 256 + t;
  const int v = i < NN ? cnt[i] : 0;
  s[t] = v;
  __syncthreads();
  for (int off = 1; off < 256; off <<= 1) {
    int add = t >= off ? s[t - off] : 0;
    __syncthreads();
    s[t] += add;
    __syncthreads();
  }
  if (i < NN) {
    rowptr[i] = s[t] - v;
    inv[i] = v > 0 ? 1.0f / (float)v : 0.0f;
  }
  if (t == 255) bsum[blockIdx.x] = s[255];
}

__global__ void k_scan_add(int* __restrict__ rowptr, const int* __restrict__ bsum) {
  __shared__ int s[256];
  const int t = threadIdx.x;
  const int v = t < SCAN_NB ? bsum[t] : 0;
  s[t] = v;
  __syncthreads();
  for (int off = 1; off < 256; off <<= 1) {
    int add = t >= off ? s[t - off] : 0;
    __syncthreads();
    s[t] += add;
    __syncthreads();
  }
  const int boff = blockIdx.x == 0 ? 0 : s[blockIdx.x - 1];
  const int i = blockIdx.x * 256 + t;
  if (i < NN) rowptr[i] += boff;
  if (i == 0) rowptr[NN] = EE;
}

// ---------------- aggregation: fp8 reads, quarter-wave per node, 8 in flight ----------------
__global__ __launch_bounds__(256) void k_gather8(
    const unsigned char* __restrict__ h8, const int* __restrict__ rowptr,
    const int* __restrict__ col, const float* __restrict__ inv,
    u16* __restrict__ agg) {
  const int tid = threadIdx.x;
  const int node = blockIdx.x * 16 + (tid >> 4);
  if (node >= NN) return;
  const int ln = tid & 15;
  const int cl = ln * 8;
  const int start = rowptr[node];
  const int end = rowptr[node + 1];
  float a[8] = {0.f, 0.f, 0.f, 0.f, 0.f, 0.f, 0.f, 0.f};
  int i = start;
  for (; i + 8 <= end; i += 8) {
    const uint2 p0 = *reinterpret_cast<const uint2*>(&h8[(size_t)col[i] * 128 + cl]);
    const uint2 p1 = *reinterpret_cast<const uint2*>(&h8[(size_t)col[i + 1] * 128 + cl]);
    const uint2 p2 = *reinterpret_cast<const uint2*>(&h8[(size_t)col[i + 2] * 128 + cl]);
    const uint2 p3 = *reinterpret_cast<const uint2*>(&h8[(size_t)col[i + 3] * 128 + cl]);
    const uint2 p4 = *reinterpret_cast<const uint2*>(&h8[(size_t)col[i + 4] * 128 + cl]);
    const uint2 p5 = *reinterpret_cast<const uint2*>(&h8[(size_t)col[i + 5] * 128 + cl]);
    const uint2 p6 = *reinterpret_cast<const uint2*>(&h8[(size_t)col[i + 6] * 128 + cl]);
    const uint2 p7 = *reinterpret_cast<const uint2*>(&h8[(size_t)col[i + 7] * 128 + cl]);
    acc_fp8(a, p0); acc_fp8(a, p1); acc_fp8(a, p2); acc_fp8(a, p3);
    acc_fp8(a, p4); acc_fp8(a, p5); acc_fp8(a, p6); acc_fp8(a, p7);
  }
  if (i + 4 <= end) {
    const uint2 p0 = *reinterpret_cast<const uint2*>(&h8[(size_t)col[i] * 128 + cl]);
    const uint2 p1 = *reinterpret_cast<const uint2*>(&h8[(size_t)col[i + 1] * 128 + cl]);
    const uint2 p2 = *reinterpret_cast<const uint2*>(&h8[(size_t)col[i + 2] * 128 + cl]);
    const uint2 p3 = *reinterpret_cast<const uint2*>(&h8[(size_t)col[i + 3] * 128 + cl]);
    acc_fp8(a, p0); acc_fp8(a, p1); acc_fp8(a, p2); acc_fp8(a, p3);
    i += 4;
  }
  for (; i < end; ++i) {
    const uint2 p0 = *reinterpret_cast<const uint2*>(&h8[(size_t)col[i] * 128 + cl]);
    acc_fp8(a, p0);
  }
  const float sc = inv[node];
#pragma unroll
  for (int k = 0; k < 8; ++k)
    agg[(size_t)node * 128 + k * 16 + ln] = f2b(a[k] * sc);
}

// ---------------- fused input MLP + fill-scatter rider ----------------
// blocks [0,MG): h = LN(relu(x@pw1+pb1)@pw2+pb2) -> hb + h8
// blocks [MG,MG+FILLB): col[rowptr[dst]+rank[e]] = src (atomic-free fill)
__global__ __launch_bounds__(256) void k_fill_mlp(
    const float* __restrict__ x, const u16* __restrict__ WT1,
    const float* __restrict__ pb1, const u16* __restrict__ WT2,
    const float* __restrict__ pb2, const float* __restrict__ lg,
    const float* __restrict__ lb, u16* __restrict__ hb,
    unsigned char* __restrict__ h8,
    const int* __restrict__ ei, const int* __restrict__ rowptr,
    const int* __restrict__ rank, int* __restrict__ col) {
  __shared__ u16 lds[32768];
  if (blockIdx.x >= MG) {
    const int e = (blockIdx.x - MG) * 256 + threadIdx.x;
    if (e < EE) {
      const int d = ei[EE + e];
      col[rowptr[d] + rank[e]] = ei[e];
    }
    return;
  }
  u16* wreg = lds;
  u16* t1r = lds + 16384;
  const int tid = threadIdx.x;
  const int wv = tid >> 6, ln = tid & 63;
  const int lrow = ln & 15, kg = ln >> 4;
  const int tbase = blockIdx.x * 128 + wv * 32;
  const int lb0 = wv * 32;
  const int ar0 = min(tbase + lrow, NN - 1);
  const int ar1 = min(tbase + 16 + lrow, NN - 1);

  stage<2048>(WT1, wreg, tid);
  __syncthreads();

  f32x4 acc0[8], acc1[8];
#pragma unroll
  for (int cf = 0; cf < 8; ++cf) {
    acc0[cf] = (f32x4){0.f, 0.f, 0.f, 0.f};
    acc1[cf] = (f32x4){0.f, 0.f, 0.f, 0.f};
  }
#pragma unroll
  for (int ks = 0; ks < 4; ++ks) {
    const float4* p0 = reinterpret_cast<const float4*>(x + (size_t)ar0 * 128 + ks * 32 + kg * 8);
    const float4* p1 = reinterpret_cast<const float4*>(x + (size_t)ar1 * 128 + ks * 32 + kg * 8);
    float4 x0 = p0[0], x1 = p0[1], y0 = p1[0], y1 = p1[1];
    s16x8 a0, a1;
    a0[0] = (short)f2b(x0.x); a0[1] = (short)f2b(x0.y); a0[2] = (short)f2b(x0.z); a0[3] = (short)f2b(x0.w);
    a0[4] = (short)f2b(x1.x); a0[5] = (short)f2b(x1.y); a0[6] = (short)f2b(x1.z); a0[7] = (short)f2b(x1.w);
    a1[0] = (short)f2b(y0.x); a1[1] = (short)f2b(y0.y); a1[2] = (short)f2b(y0.z); a1[3] = (short)f2b(y0.w);
    a1[4] = (short)f2b(y1.x); a1[5] = (short)f2b(y1.y); a1[6] = (short)f2b(y1.z); a1[7] = (short)f2b(y1.w);
#pragma unroll
    for (int cf = 0; cf < 8; ++cf) {
      const s16x8 bf = ldsw(wreg, cf * 16 + lrow, ks * 4 + kg);
      acc0[cf] = __builtin_amdgcn_mfma_f32_16x16x32_bf16(a0, bf, acc0[cf], 0, 0, 0);
      acc1[cf] = __builtin_amdgcn_mfma_f32_16x16x32_bf16(a1, bf, acc1[cf], 0, 0, 0);
    }
  }
  {
    float bb[8];
#pragma unroll
    for (int cf = 0; cf < 8; ++cf) bb[cf] = pb1[cf * 16 + lrow];
#pragma unroll
    for (int t = 0; t < 2; ++t)
#pragma unroll
      for (int j = 0; j < 4; ++j) {
        const int lr = lb0 + t * 16 + kg * 4 + j;
#pragma unroll
        for (int cf = 0; cf < 8; ++cf)
          stsw(t1r, lr, cf * 16 + lrow, f2b(fmaxf((t ? acc1[cf][j] : acc0[cf][j]) + bb[cf], 0.0f)));
      }
  }
  __syncthreads();
  stage<2048>(WT2, wreg, tid);
  __syncthreads();

  f32x4 c0[8], c1[8];
#pragma unroll
  for (int cf = 0; cf < 8; ++cf) {
    c0[cf] = (f32x4){0.f, 0.f, 0.f, 0.f};
    c1[cf] = (f32x4){0.f, 0.f, 0.f, 0.f};
  }
#pragma unroll
  for (int ks = 0; ks < 4; ++ks) {
    const s16x8 a0 = ldsw(t1r, lb0 + lrow, ks * 4 + kg);
    const s16x8 a1 = ldsw(t1r, lb0 + 16 + lrow, ks * 4 + kg);
#pragma unroll
    for (int cf = 0; cf < 8; ++cf) {
      const s16x8 bf = ldsw(wreg, cf * 16 + lrow, ks * 4 + kg);
      c0[cf] = __builtin_amdgcn_mfma_f32_16x16x32_bf16(a0, bf, c0[cf], 0, 0, 0);
      c1[cf] = __builtin_amdgcn_mfma_f32_16x16x32_bf16(a1, bf, c1[cf], 0, 0, 0);
    }
  }

  float bb[8], gm[8], gb[8];
#pragma unroll
  for (int cf = 0; cf < 8; ++cf) {
    const int c = cf * 16 + lrow;
    bb[cf] = pb2[c];
    gm[cf] = lg[c];
    gb[cf] = lb[c];
  }
#pragma unroll
  for (int t = 0; t < 2; ++t)
#pragma unroll
    for (int j = 0; j < 4; ++j) {
      const int r = tbase + t * 16 + kg * 4 + j;
      float v[8];
#pragma unroll
      for (int cf = 0; cf < 8; ++cf) v[cf] = (t ? c1[cf][j] : c0[cf][j]) + bb[cf];
      float s = 0.f;
#pragma unroll
      for (int cf = 0; cf < 8; ++cf) s += v[cf];
      s += __shfl_xor(s, 1); s += __shfl_xor(s, 2);
      s += __shfl_xor(s, 4); s += __shfl_xor(s, 8);
      const float mu = s * (1.0f / 128);
      float q = 0.f;
#pragma unroll
      for (int cf = 0; cf < 8; ++cf) { const float d = v[cf] - mu; q += d * d; }
      q += __shfl_xor(q, 1); q += __shfl_xor(q, 2);
      q += __shfl_xor(q, 4); q += __shfl_xor(q, 8);
      const float istd = rsqrtf(q * (1.0f / 128) + 1e-5f);
      if (r < NN) {
        float ov[8];
#pragma unroll
        for (int cf = 0; cf < 8; ++cf) {
          ov[cf] = (v[cf] - mu) * istd * gm[cf] + gb[cf];
          hb[(size_t)r * 128 + cf * 16 + lrow] = f2b(ov[cf]);
        }
        *reinterpret_cast<uint2*>(&h8[(size_t)r * 128 + lrow * 8]) = pack_fp8(ov);
      }
    }
}

// ---------------- SAGE layer 0: h' = LN(h + relu(agg@WL + bl + h@WR)) -> hb, h8 ----------------
__global__ __launch_bounds__(256) void k_sage0(
    const u16* __restrict__ agg, const u16* __restrict__ hb,
    const u16* __restrict__ WTl, const u16* __restrict__ WTr,
    const float* __restrict__ bl, const float* __restrict__ lg,
    const float* __restrict__ lb, u16* __restrict__ hb_out,
    unsigned char* __restrict__ h8) {
  __shared__ u16 lds[32768];
  u16* wl = lds;
  u16* wr = lds + 16384;
  const int tid = threadIdx.x;
  const int wv = tid >> 6, ln = tid & 63;
  const int lrow = ln & 15, kg = ln >> 4;
  const int tbase = blockIdx.x * 128 + wv * 32;
  const int ar0 = min(tbase + lrow, NN - 1);
  const int ar1 = min(tbase + 16 + lrow, NN - 1);

  stage<2048>(WTl, wl, tid);
  stage<2048>(WTr, wr, tid);
  __syncthreads();

  f32x4 acc0[8], acc1[8];
#pragma unroll
  for (int cf = 0; cf < 8; ++cf) {
    acc0[cf] = (f32x4){0.f, 0.f, 0.f, 0.f};
    acc1[cf] = (f32x4){0.f, 0.f, 0.f, 0.f};
  }
#pragma unroll
  for (int ks = 0; ks < 4; ++ks) {
    const s16x8 g0 = *reinterpret_cast<const s16x8*>(agg + (size_t)ar0 * 128 + ks * 32 + kg * 8);
    const s16x8 g1 = *reinterpret_cast<const s16x8*>(agg + (size_t)ar1 * 128 + ks * 32 + kg * 8);
    const s16x8 h0 = *reinterpret_cast<const s16x8*>(hb + (size_t)ar0 * 128 + ks * 32 + kg * 8);
    const s16x8 h1 = *reinterpret_cast<const s16x8*>(hb + (size_t)ar1 * 128 + ks * 32 + kg * 8);
#pragma unroll
    for (int cf = 0; cf < 8; ++cf) {
      const s16x8 bwl = ldsw(wl, cf * 16 + lrow, ks * 4 + kg);
      const s16x8 bwr = ldsw(wr, cf * 16 + lrow, ks * 4 + kg);
      acc0[cf] = __builtin_amdgcn_mfma_f32_16x16x32_bf16(g0, bwl, acc0[cf], 0, 0, 0);
      acc0[cf] = __builtin_amdgcn_mfma_f32_16x16x32_bf16(h0, bwr, acc0[cf], 0, 0, 0);
      acc1[cf] = __builtin_amdgcn_mfma_f32_16x16x32_bf16(g1, bwl, acc1[cf], 0, 0, 0);
      acc1[cf] = __builtin_amdgcn_mfma_f32_16x16x32_bf16(h1, bwr, acc1[cf], 0, 0, 0);
    }
  }

  float bb[8], gm[8], gb[8];
#pragma unroll
  for (int cf = 0; cf < 8; ++cf) {
    const int c = cf * 16 + lrow;
    bb[cf] = bl[c];
    gm[cf] = lg[c];
    gb[cf] = lb[c];
  }
#pragma unroll
  for (int t = 0; t < 2; ++t)
#pragma unroll
    for (int j = 0; j < 4; ++j) {
      const int r = tbase + t * 16 + kg * 4 + j;
      const int rs = r < NN ? r : NN - 1;
      float v[8];
#pragma unroll
      for (int cf = 0; cf < 8; ++cf) {
        const int c = cf * 16 + lrow;
        v[cf] = b2f(hb[(size_t)rs * 128 + c]) +
                fmaxf((t ? acc1[cf][j] : acc0[cf][j]) + bb[cf], 0.0f);
      }
      float s = 0.f;
#pragma unroll
      for (int cf = 0; cf < 8; ++cf) s += v[cf];
      s += __shfl_xor(s, 1); s += __shfl_xor(s, 2);
      s += __shfl_xor(s, 4); s += __shfl_xor(s, 8);
      const float mu = s * (1.0f / 128);
      float q = 0.f;
#pragma unroll
      for (int cf = 0; cf < 8; ++cf) { const float d = v[cf] - mu; q += d * d; }
      q += __shfl_xor(q, 1); q += __shfl_xor(q, 2);
      q += __shfl_xor(q, 4); q += __shfl_xor(q, 8);
      const float istd = rsqrtf(q * (1.0f / 128) + 1e-5f);
      if (r < NN) {
        float ov[8];
#pragma unroll
        for (int cf = 0; cf < 8; ++cf) {
          ov[cf] = (v[cf] - mu) * istd * gm[cf] + gb[cf];
          hb_out[(size_t)r * 128 + cf * 16 + lrow] = f2b(ov[cf]);
        }
        *reinterpret_cast<uint2*>(&h8[(size_t)r * 128 + lrow * 8]) = pack_fp8(ov);
      }
    }
}

// ---------------- SAGE layer 1 + classifier fused ----------------
// LDS: [0,16384)=WTl -> th tile; [16384,32768)=WTr -> Wc1; [32768,37888)=Wc2
__global__ __launch_bounds__(256) void k_sage_cls(
    const u16* __restrict__ agg, const u16* __restrict__ hb,
    const u16* __restrict__ WTl, const u16* __restrict__ WTr,
    const float* __restrict__ bl, const float* __restrict__ lg,
    const float* __restrict__ lb,
    const u16* __restrict__ Wc1, const float* __restrict__ cb1,
    const u16* __restrict__ Wc2, const float* __restrict__ cb2,
    float* __restrict__ out_h, float* __restrict__ logits) {
  __shared__ u16 lds[37888];
  u16* wl = lds;          // phase A: WTl ; phase B: th tile (128x128)
  u16* wr = lds + 16384;  // phase A: WTr ; phase B: Wc1
  u16* w2 = lds + 32768;  // Wc2 (40x128)
  const int tid = threadIdx.x;
  const int wv = tid >> 6, ln = tid & 63;
  const int lrow = ln & 15, kg = ln >> 4;
  const int tbase = blockIdx.x * 128 + wv * 32;
  const int lb0 = wv * 32;
  const int ar0 = min(tbase + lrow, NN - 1);
  const int ar1 = min(tbase + 16 + lrow, NN - 1);

  stage<2048>(WTl, wl, tid);
  stage<2048>(WTr, wr, tid);
  stage<640>(Wc2, w2, tid);
  __syncthreads();

  f32x4 acc0[8], acc1[8];
#pragma unroll
  for (int cf = 0; cf < 8; ++cf) {
    acc0[cf] = (f32x4){0.f, 0.f, 0.f, 0.f};
    acc1[cf] = (f32x4){0.f, 0.f, 0.f, 0.f};
  }
#pragma unroll
  for (int ks = 0; ks < 4; ++ks) {
    const s16x8 g0 = *reinterpret_cast<const s16x8*>(agg + (size_t)ar0 * 128 + ks * 32 + kg * 8);
    const s16x8 g1 = *reinterpret_cast<const s16x8*>(agg + (size_t)ar1 * 128 + ks * 32 + kg * 8);
    const s16x8 h0 = *reinterpret_cast<const s16x8*>(hb + (size_t)ar0 * 128 + ks * 32 + kg * 8);
    const s16x8 h1 = *reinterpret_cast<const s16x8*>(hb + (size_t)ar1 * 128 + ks * 32 + kg * 8);
#pragma unroll
    for (int cf = 0; cf < 8; ++cf) {
      const s16x8 bwl = ldsw(wl, cf * 16 + lrow, ks * 4 + kg);
      const s16x8 bwr = ldsw(wr, cf * 16 + lrow, ks * 4 + kg);
      acc0[cf] = __builtin_amdgcn_mfma_f32_16x16x32_bf16(g0, bwl, acc0[cf], 0, 0, 0);
      acc0[cf] = __builtin_amdgcn_mfma_f32_16x16x32_bf16(h0, bwr, acc0[cf], 0, 0, 0);
      acc1[cf] = __builtin_amdgcn_mfma_f32_16x16x32_bf16(g1, bwl, acc1[cf], 0, 0, 0);
      acc1[cf] = __builtin_amdgcn_mfma_f32_16x16x32_bf16(h1, bwr, acc1[cf], 0, 0, 0);
    }
  }
  __syncthreads();  // all waves done reading WTl/WTr

  {
    float bb[8], gm[8], gb[8];
#pragma unroll
    for (int cf = 0; cf < 8; ++cf) {
      const int c = cf * 16 + lrow;
      bb[cf] = bl[c];
      gm[cf] = lg[c];
      gb[cf] = lb[c];
    }
#pragma unroll
    for (int t = 0; t < 2; ++t)
#pragma unroll
      for (int j = 0; j < 4; ++j) {
        const int r = tbase + t * 16 + kg * 4 + j;
        const int rs = r < NN ? r : NN - 1;
        const int lr = lb0 + t * 16 + kg * 4 + j;
        float v[8];
#pragma unroll
        for (int cf = 0; cf < 8; ++cf) {
          const int c = cf * 16 + lrow;
          v[cf] = b2f(hb[(size_t)rs * 128 + c]) +
                  fmaxf((t ? acc1[cf][j] : acc0[cf][j]) + bb[cf], 0.0f);
        }
        float s = 0.f;
#pragma unroll
        for (int cf = 0; cf < 8; ++cf) s += v[cf];
        s += __shfl_xor(s, 1); s += __shfl_xor(s, 2);
        s += __shfl_xor(s, 4); s += __shfl_xor(s, 8);
        const float mu = s * (1.0f / 128);
        float q = 0.f;
#pragma unroll
        for (int cf = 0; cf < 8; ++cf) { const float d = v[cf] - mu; q += d * d; }
        q += __shfl_xor(q, 1); q += __shfl_xor(q, 2);
        q += __shfl_xor(q, 4); q += __shfl_xor(q, 8);
        const float istd = rsqrtf(q * (1.0f / 128) + 1e-5f);
#pragma unroll
        for (int cf = 0; cf < 8; ++cf) {
          const int c = cf * 16 + lrow;
          const float o = (v[cf] - mu) * istd * gm[cf] + gb[cf];
          stsw(wl, lr, c, f2b(o));
          if (r < NN) out_h[(size_t)r * 128 + c] = o;
        }
      }
  }
  stage<2048>(Wc1, wr, tid);  // Wc1 over WTr (all reads done at barrier above)
  __syncthreads();

  // classifier: per wave, its own two 16-row th tiles
  float cb1v[8];
#pragma unroll
  for (int cf = 0; cf < 8; ++cf) cb1v[cf] = cb1[cf * 16 + lrow];

#pragma unroll
  for (int t = 0; t < 2; ++t) {
    const int rb = lb0 + t * 16;
    f32x4 a3[8];
#pragma unroll
    for (int cf = 0; cf < 8; ++cf) a3[cf] = (f32x4){0.f, 0.f, 0.f, 0.f};
#pragma unroll
    for (int ks = 0; ks < 4; ++ks) {
      const s16x8 a = ldsw(wl, rb + lrow, ks * 4 + kg);
#pragma unroll
      for (int cf = 0; cf < 8; ++cf) {
        const s16x8 bf = ldsw(wr, cf * 16 + lrow, ks * 4 + kg);
        a3[cf] = __builtin_amdgcn_mfma_f32_16x16x32_bf16(a, bf, a3[cf], 0, 0, 0);
      }
    }
    // t3 overwrites this wave's own th rows
#pragma unroll
    for (int j = 0; j < 4; ++j)
#pragma unroll
      for (int cf = 0; cf < 8; ++cf)
        stsw(wl, rb + kg * 4 + j, cf * 16 + lrow, f2b(fmaxf(a3[cf][j] + cb1v[cf], 0.0f)));

    f32x4 a2[3];
#pragma unroll
    for (int cf = 0; cf < 3; ++cf) a2[cf] = (f32x4){0.f, 0.f, 0.f, 0.f};
#pragma unroll
    for (int ks = 0; ks < 4; ++ks) {
      const s16x8 a = ldsw(wl, rb + lrow, ks * 4 + kg);
#pragma unroll
      for (int cf = 0; cf < 3; ++cf) {
        const int bn = min(cf * 16 + lrow, CC - 1);
        const s16x8 bf = ldsw(w2, bn, ks * 4 + kg);
        a2[cf] = __builtin_amdgcn_mfma_f32_16x16x32_bf16(a, bf, a2[cf], 0, 0, 0);
      }
    }
#pragma unroll
    for (int j = 0; j < 4; ++j) {
      const int r = tbase + t * 16 + kg * 4 + j;
      if (r < NN) {
#pragma unroll
        for (int cf = 0; cf < 3; ++cf) {
          const int c = cf * 16 + lrow;
          if (c < CC) logits[(size_t)r * CC + c] = a2[cf][j] + cb2[c];
        }
      }
    }
  }
}

}  // namespace

extern "C" void kernel_launch(void* const* d_in, const int* in_sizes, int n_in,
                              void* d_out, int out_size, void* d_ws, size_t ws_size,
                              hipStream_t stream) {
  (void)in_sizes; (void)n_in; (void)out_size; (void)ws_size;
  const float* x   = (const float*)d_in[0];
  const int*   ei  = (const int*)d_in[1];
  const float* pw1 = (const float*)d_in[2];
  const float* pb1 = (const float*)d_in[3];
  const float* pw2 = (const float*)d_in[4];
  const float* pb2 = (const float*)d_in[5];
  const float* ing = (const float*)d_in[6];
  const float* inb = (const float*)d_in[7];
  const float* swl = (const float*)d_in[8];
  const float* sbl = (const float*)d_in[9];
  const float* swr = (const float*)d_in[10];
  const float* lng = (const float*)d_in[11];
  const float* lnb = (const float*)d_in[12];
  const float* cw1 = (const float*)d_in[13];
  const float* cb1 = (const float*)d_in[14];
  const float* cw2 = (const float*)d_in[15];
  const float* cb2 = (const float*)d_in[16];

  float* out_logits = (float*)d_out;
  float* out_h = out_logits + (size_t)NN * CC;

  const size_t NNH = (size_t)NN * HH;
  u16*   hb   = (u16*)d_ws;                // 12.8 MB
  u16*   bufA = hb + NNH;                  // 12.8 MB (agg)
  u16*   wt   = bufA + NNH;                // 256 KB
  int*   cnt    = (int*)(wt + 8 * 16384);  // NN
  float* inv    = (float*)(cnt + NN);      // NN
  int*   rowptr = (int*)(inv + NN);        // NN+1
  int*   bsum   = rowptr + NN + 1;         // 256
  int*   colarr = bsum + 256;              // EE
  int*   rankar = colarr + EE;             // EE
  unsigned char* h8 = (unsigned char*)(rankar + EE);  // NN*128 bytes (fp8)

  // ---- zero cnt, then weight transpose + degree rider ----
  k_zero<<<SCAN_NB, 256, 0, stream>>>(cnt);
  k_pre_deg<<<WTB + FILLB, 256, 0, stream>>>(
      pw1, pw2, swl, swr, cw1, cw2, wt, ei, cnt, rankar);

  // ---- CSR scan ----
  k_scan_block<<<SCAN_NB, 256, 0, stream>>>(cnt, rowptr, bsum, inv);
  k_scan_add<<<SCAN_NB, 256, 0, stream>>>(rowptr, bsum);

  // ---- input MLP with fill-scatter ridden in ----
  k_fill_mlp<<<MG + FILLB, 256, 0, stream>>>(
      x, wt + 0 * 16384, pb1, wt + 1 * 16384, pb2, ing, inb, hb, h8,
      ei, rowptr, rankar, colarr);

  // layer 0 (fp8 gather)
  k_gather8<<<(NN + 15) / 16, 256, 0, stream>>>(h8, rowptr, colarr, inv, bufA);
  k_sage0<<<(NN + 127) / 128, 256, 0, stream>>>(
      bufA, hb, wt + 2 * 16384, wt + 4 * 16384, sbl, lng, lnb, hb, h8);

  // layer 1 + classifier
  k_gather8<<<(NN + 15) / 16, 256, 0, stream>>>(h8, rowptr, colarr, inv, bufA);
  k_sage_cls<<<(NN + 127) / 128, 256, 0, stream>>>(
      bufA, hb, wt + 3 * 16384, wt + 5 * 16384, sbl + HH, lng + HH, lnb + HH,
      wt + 6 * 16384, cb1, wt + 7 * 16384, cb2, out_h, out_logits);
}

// Round 15
// 142.778 us; speedup vs baseline: 1.0462x; 1.0462x over previous
//
#include <hip/hip_runtime.h>

// GNN encoder: input MLP + LN, 2x SAGEConv(mean) + ReLU + residual + LN, classifier MLP.
// Round 15: exact revert to round 13 (best: 143.0us). Round-14's fill/degree rider swap
// regressed (+6.4us): fill doesn't hide under the 391-block mlp; degree does.
//  - k_pre: WT1/WT2 transpose + cnt zero
//  - k_mlp_deg: mlp + degree rider + wt slots 2..7 rider
//  - scan_block -> scan_add -> k_fill (atomic-free, rank-based)
//  - fp8 gather path (h8, lane-permuted), sage0, sage_cls

namespace {

constexpr int NN = 50000;
constexpr int EE = 640000;
constexpr int HH = 128;
constexpr int CC = 40;
constexpr int SCAN_NB = (NN + 255) / 256;  // 196
constexpr int MG = (NN + 127) / 128;       // 391 (mlp blocks)
constexpr int DEGB = (EE + 255) / 256;     // 2500 (degree blocks)
constexpr int WPB = (5 * 16384 + CC * 128 + 255) / 256;  // 340 (wt slots 2..7)

typedef unsigned short u16;
typedef __attribute__((ext_vector_type(8))) short s16x8;
typedef __attribute__((ext_vector_type(8))) unsigned short u16x8;
typedef __attribute__((ext_vector_type(4))) float f32x4;
typedef __attribute__((ext_vector_type(2))) float f32x2;

__device__ __forceinline__ float b2f(u16 h) {
  unsigned int u = ((unsigned int)h) << 16;
  return __builtin_bit_cast(float, u);
}
__device__ __forceinline__ u16 f2b(float f) {
  unsigned int u = __builtin_bit_cast(unsigned int, f);
  u += 0x7FFFu + ((u >> 16) & 1u);
  return (u16)(u >> 16);
}

// pack 8 floats -> 8 fp8 e4m3 bytes (v[q] -> byte q)
__device__ __forceinline__ uint2 pack_fp8(const float* v) {
  int w0 = 0, w1 = 0;
  w0 = __builtin_amdgcn_cvt_pk_fp8_f32(v[0], v[1], w0, false);
  w0 = __builtin_amdgcn_cvt_pk_fp8_f32(v[2], v[3], w0, true);
  w1 = __builtin_amdgcn_cvt_pk_fp8_f32(v[4], v[5], w1, false);
  w1 = __builtin_amdgcn_cvt_pk_fp8_f32(v[6], v[7], w1, true);
  return make_uint2((unsigned)w0, (unsigned)w1);
}
// accumulate 8 fp8 bytes into a[0..7]
__device__ __forceinline__ void acc_fp8(float* a, uint2 p) {
  const f32x2 f0 = __builtin_amdgcn_cvt_pk_f32_fp8((int)p.x, false);
  const f32x2 f1 = __builtin_amdgcn_cvt_pk_f32_fp8((int)p.x, true);
  const f32x2 f2 = __builtin_amdgcn_cvt_pk_f32_fp8((int)p.y, false);
  const f32x2 f3 = __builtin_amdgcn_cvt_pk_f32_fp8((int)p.y, true);
  a[0] += f0.x; a[1] += f0.y; a[2] += f1.x; a[3] += f1.y;
  a[4] += f2.x; a[5] += f2.y; a[6] += f3.x; a[7] += f3.y;
}

// ---- swizzled LDS tile: row n, 16B-granule k0; slot = k0 ^ (n&15) ----
__device__ __forceinline__ s16x8 ldsw(const u16* base, int n, int k0) {
  return *reinterpret_cast<const s16x8*>(base + n * 128 + (((k0 ^ n) & 15) << 3));
}
__device__ __forceinline__ void stsw(u16* base, int r, int c, u16 v) {
  base[r * 128 + ((((c >> 3) ^ r) & 15) << 3) + (c & 7)] = v;
}
template <int NGRAN>
__device__ __forceinline__ void stage(const u16* __restrict__ src, u16* dst, int tid) {
#pragma unroll
  for (int i = 0; i < (NGRAN + 255) / 256; ++i) {
    const int gi = i * 256 + tid;
    if ((NGRAN & 255) == 0 || gi < NGRAN) {
      const int n = gi >> 4, k0 = gi & 15;
      const u16x8 v = *reinterpret_cast<const u16x8*>(src + gi * 8);
      *reinterpret_cast<u16x8*>(dst + n * 128 + (((k0 ^ n) & 15) << 3)) = v;
    }
  }
}

// ---------------- prelude: WT1/WT2 transpose + cnt zero ----------------
__global__ void k_pre(const float* __restrict__ pw1, const float* __restrict__ pw2,
                      u16* __restrict__ wt, int* __restrict__ cnt) {
  int flat = blockIdx.x * 256 + threadIdx.x;
  const int TWO = 2 * 16384;
  if (flat < TWO) {
    int id = flat >> 14;
    int off = flat & 16383;
    int n = off >> 7, k = off & 127;
    const float* s = id == 0 ? pw1 : pw2;
    wt[(size_t)id * 16384 + n * 128 + k] = f2b(s[k * 128 + n]);
  } else {
    int i = flat - TWO;
    if (i < NN) cnt[i] = 0;
  }
}

// ---------------- CSR scan / fill ----------------
__global__ void k_scan_block(const int* __restrict__ cnt, int* __restrict__ rowptr,
                             int* __restrict__ bsum, float* __restrict__ inv) {
  __shared__ int s[256];
  const int t = threadIdx.x;
  const int i = blockIdx.x * 256 + t;
  const int v = i < NN ? cnt[i] : 0;
  s[t] = v;
  __syncthreads();
  for (int off = 1; off < 256; off <<= 1) {
    int add = t >= off ? s[t - off] : 0;
    __syncthreads();
    s[t] += add;
    __syncthreads();
  }
  if (i < NN) {
    rowptr[i] = s[t] - v;
    inv[i] = v > 0 ? 1.0f / (float)v : 0.0f;
  }
  if (t == 255) bsum[blockIdx.x] = s[255];
}

__global__ void k_scan_add(int* __restrict__ rowptr, const int* __restrict__ bsum) {
  __shared__ int s[256];
  const int t = threadIdx.x;
  const int v = t < SCAN_NB ? bsum[t] : 0;
  s[t] = v;
  __syncthreads();
  for (int off = 1; off < 256; off <<= 1) {
    int add = t >= off ? s[t - off] : 0;
    __syncthreads();
    s[t] += add;
    __syncthreads();
  }
  const int boff = blockIdx.x == 0 ? 0 : s[blockIdx.x - 1];
  const int i = blockIdx.x * 256 + t;
  if (i < NN) rowptr[i] += boff;
  if (i == 0) rowptr[NN] = EE;
}

// atomic-free fill: position = rowptr[dst] + rank[e]
__global__ void k_fill(const int* __restrict__ ei, const int* __restrict__ rowptr,
                       const int* __restrict__ rank, int* __restrict__ col) {
  int e = blockIdx.x * 256 + threadIdx.x;
  if (e >= EE) return;
  const int d = ei[EE + e];
  col[rowptr[d] + rank[e]] = ei[e];
}

// ---------------- aggregation: fp8 reads, quarter-wave per node, 8 in flight ----------------
__global__ __launch_bounds__(256) void k_gather8(
    const unsigned char* __restrict__ h8, const int* __restrict__ rowptr,
    const int* __restrict__ col, const float* __restrict__ inv,
    u16* __restrict__ agg) {
  const int tid = threadIdx.x;
  const int node = blockIdx.x * 16 + (tid >> 4);
  if (node >= NN) return;
  const int ln = tid & 15;
  const int cl = ln * 8;
  const int start = rowptr[node];
  const int end = rowptr[node + 1];
  float a[8] = {0.f, 0.f, 0.f, 0.f, 0.f, 0.f, 0.f, 0.f};
  int i = start;
  for (; i + 8 <= end; i += 8) {
    const uint2 p0 = *reinterpret_cast<const uint2*>(&h8[(size_t)col[i] * 128 + cl]);
    const uint2 p1 = *reinterpret_cast<const uint2*>(&h8[(size_t)col[i + 1] * 128 + cl]);
    const uint2 p2 = *reinterpret_cast<const uint2*>(&h8[(size_t)col[i + 2] * 128 + cl]);
    const uint2 p3 = *reinterpret_cast<const uint2*>(&h8[(size_t)col[i + 3] * 128 + cl]);
    const uint2 p4 = *reinterpret_cast<const uint2*>(&h8[(size_t)col[i + 4] * 128 + cl]);
    const uint2 p5 = *reinterpret_cast<const uint2*>(&h8[(size_t)col[i + 5] * 128 + cl]);
    const uint2 p6 = *reinterpret_cast<const uint2*>(&h8[(size_t)col[i + 6] * 128 + cl]);
    const uint2 p7 = *reinterpret_cast<const uint2*>(&h8[(size_t)col[i + 7] * 128 + cl]);
    acc_fp8(a, p0); acc_fp8(a, p1); acc_fp8(a, p2); acc_fp8(a, p3);
    acc_fp8(a, p4); acc_fp8(a, p5); acc_fp8(a, p6); acc_fp8(a, p7);
  }
  if (i + 4 <= end) {
    const uint2 p0 = *reinterpret_cast<const uint2*>(&h8[(size_t)col[i] * 128 + cl]);
    const uint2 p1 = *reinterpret_cast<const uint2*>(&h8[(size_t)col[i + 1] * 128 + cl]);
    const uint2 p2 = *reinterpret_cast<const uint2*>(&h8[(size_t)col[i + 2] * 128 + cl]);
    const uint2 p3 = *reinterpret_cast<const uint2*>(&h8[(size_t)col[i + 3] * 128 + cl]);
    acc_fp8(a, p0); acc_fp8(a, p1); acc_fp8(a, p2); acc_fp8(a, p3);
    i += 4;
  }
  for (; i < end; ++i) {
    const uint2 p0 = *reinterpret_cast<const uint2*>(&h8[(size_t)col[i] * 128 + cl]);
    acc_fp8(a, p0);
  }
  const float sc = inv[node];
  // a[k] corresponds to real column k*16 + ln (permuted h8 layout)
#pragma unroll
  for (int k = 0; k < 8; ++k)
    agg[(size_t)node * 128 + k * 16 + ln] = f2b(a[k] * sc);
}

// ---------------- fused input MLP + riders (degree, wt slots 2..7) ----------------
__global__ __launch_bounds__(256) void k_mlp_deg(
    const float* __restrict__ x, const u16* __restrict__ WT1,
    const float* __restrict__ pb1, const u16* __restrict__ WT2,
    const float* __restrict__ pb2, const float* __restrict__ lg,
    const float* __restrict__ lb, u16* __restrict__ hb,
    unsigned char* __restrict__ h8,
    const int* __restrict__ ei, int* __restrict__ cnt, int* __restrict__ rank,
    const float* __restrict__ swl, const float* __restrict__ swr,
    const float* __restrict__ cw1, const float* __restrict__ cw2,
    u16* __restrict__ wt) {
  __shared__ u16 lds[32768];
  if (blockIdx.x >= MG) {
    const int rb = blockIdx.x - MG;
    if (rb < DEGB) {
      const int e = rb * 256 + threadIdx.x;
      if (e < EE) rank[e] = atomicAdd(&cnt[ei[EE + e]], 1);
    } else {
      const int flat = (rb - DEGB) * 256 + threadIdx.x;
      const int FIVE = 5 * 16384;
      if (flat < FIVE) {
        int id = flat >> 14;  // 0..4 -> slots 2..6
        int off = flat & 16383;
        int n = off >> 7, k = off & 127;
        const float* s;
        switch (id) {
          case 0: s = swl; break;
          case 1: s = swl + 16384; break;
          case 2: s = swr; break;
          case 3: s = swr + 16384; break;
          default: s = cw1; break;
        }
        wt[(size_t)(id + 2) * 16384 + n * 128 + k] = f2b(s[k * 128 + n]);
      } else {
        int off = flat - FIVE;
        if (off < CC * 128) {
          int n = off >> 7, k = off & 127;
          wt[(size_t)7 * 16384 + n * 128 + k] = f2b(cw2[k * CC + n]);
        }
      }
    }
    return;
  }
  u16* wreg = lds;
  u16* t1r = lds + 16384;
  const int tid = threadIdx.x;
  const int wv = tid >> 6, ln = tid & 63;
  const int lrow = ln & 15, kg = ln >> 4;
  const int tbase = blockIdx.x * 128 + wv * 32;
  const int lb0 = wv * 32;
  const int ar0 = min(tbase + lrow, NN - 1);
  const int ar1 = min(tbase + 16 + lrow, NN - 1);

  stage<2048>(WT1, wreg, tid);
  __syncthreads();

  f32x4 acc0[8], acc1[8];
#pragma unroll
  for (int cf = 0; cf < 8; ++cf) {
    acc0[cf] = (f32x4){0.f, 0.f, 0.f, 0.f};
    acc1[cf] = (f32x4){0.f, 0.f, 0.f, 0.f};
  }
#pragma unroll
  for (int ks = 0; ks < 4; ++ks) {
    const float4* p0 = reinterpret_cast<const float4*>(x + (size_t)ar0 * 128 + ks * 32 + kg * 8);
    const float4* p1 = reinterpret_cast<const float4*>(x + (size_t)ar1 * 128 + ks * 32 + kg * 8);
    float4 x0 = p0[0], x1 = p0[1], y0 = p1[0], y1 = p1[1];
    s16x8 a0, a1;
    a0[0] = (short)f2b(x0.x); a0[1] = (short)f2b(x0.y); a0[2] = (short)f2b(x0.z); a0[3] = (short)f2b(x0.w);
    a0[4] = (short)f2b(x1.x); a0[5] = (short)f2b(x1.y); a0[6] = (short)f2b(x1.z); a0[7] = (short)f2b(x1.w);
    a1[0] = (short)f2b(y0.x); a1[1] = (short)f2b(y0.y); a1[2] = (short)f2b(y0.z); a1[3] = (short)f2b(y0.w);
    a1[4] = (short)f2b(y1.x); a1[5] = (short)f2b(y1.y); a1[6] = (short)f2b(y1.z); a1[7] = (short)f2b(y1.w);
#pragma unroll
    for (int cf = 0; cf < 8; ++cf) {
      const s16x8 bf = ldsw(wreg, cf * 16 + lrow, ks * 4 + kg);
      acc0[cf] = __builtin_amdgcn_mfma_f32_16x16x32_bf16(a0, bf, acc0[cf], 0, 0, 0);
      acc1[cf] = __builtin_amdgcn_mfma_f32_16x16x32_bf16(a1, bf, acc1[cf], 0, 0, 0);
    }
  }
  {
    float bb[8];
#pragma unroll
    for (int cf = 0; cf < 8; ++cf) bb[cf] = pb1[cf * 16 + lrow];
#pragma unroll
    for (int t = 0; t < 2; ++t)
#pragma unroll
      for (int j = 0; j < 4; ++j) {
        const int lr = lb0 + t * 16 + kg * 4 + j;
#pragma unroll
        for (int cf = 0; cf < 8; ++cf)
          stsw(t1r, lr, cf * 16 + lrow, f2b(fmaxf((t ? acc1[cf][j] : acc0[cf][j]) + bb[cf], 0.0f)));
      }
  }
  __syncthreads();
  stage<2048>(WT2, wreg, tid);
  __syncthreads();

  f32x4 c0[8], c1[8];
#pragma unroll
  for (int cf = 0; cf < 8; ++cf) {
    c0[cf] = (f32x4){0.f, 0.f, 0.f, 0.f};
    c1[cf] = (f32x4){0.f, 0.f, 0.f, 0.f};
  }
#pragma unroll
  for (int ks = 0; ks < 4; ++ks) {
    const s16x8 a0 = ldsw(t1r, lb0 + lrow, ks * 4 + kg);
    const s16x8 a1 = ldsw(t1r, lb0 + 16 + lrow, ks * 4 + kg);
#pragma unroll
    for (int cf = 0; cf < 8; ++cf) {
      const s16x8 bf = ldsw(wreg, cf * 16 + lrow, ks * 4 + kg);
      c0[cf] = __builtin_amdgcn_mfma_f32_16x16x32_bf16(a0, bf, c0[cf], 0, 0, 0);
      c1[cf] = __builtin_amdgcn_mfma_f32_16x16x32_bf16(a1, bf, c1[cf], 0, 0, 0);
    }
  }

  float bb[8], gm[8], gb[8];
#pragma unroll
  for (int cf = 0; cf < 8; ++cf) {
    const int c = cf * 16 + lrow;
    bb[cf] = pb2[c];
    gm[cf] = lg[c];
    gb[cf] = lb[c];
  }
#pragma unroll
  for (int t = 0; t < 2; ++t)
#pragma unroll
    for (int j = 0; j < 4; ++j) {
      const int r = tbase + t * 16 + kg * 4 + j;
      float v[8];
#pragma unroll
      for (int cf = 0; cf < 8; ++cf) v[cf] = (t ? c1[cf][j] : c0[cf][j]) + bb[cf];
      float s = 0.f;
#pragma unroll
      for (int cf = 0; cf < 8; ++cf) s += v[cf];
      s += __shfl_xor(s, 1); s += __shfl_xor(s, 2);
      s += __shfl_xor(s, 4); s += __shfl_xor(s, 8);
      const float mu = s * (1.0f / 128);
      float q = 0.f;
#pragma unroll
      for (int cf = 0; cf < 8; ++cf) { const float d = v[cf] - mu; q += d * d; }
      q += __shfl_xor(q, 1); q += __shfl_xor(q, 2);
      q += __shfl_xor(q, 4); q += __shfl_xor(q, 8);
      const float istd = rsqrtf(q * (1.0f / 128) + 1e-5f);
      if (r < NN) {
        float ov[8];
#pragma unroll
        for (int cf = 0; cf < 8; ++cf) {
          ov[cf] = (v[cf] - mu) * istd * gm[cf] + gb[cf];
          hb[(size_t)r * 128 + cf * 16 + lrow] = f2b(ov[cf]);
        }
        *reinterpret_cast<uint2*>(&h8[(size_t)r * 128 + lrow * 8]) = pack_fp8(ov);
      }
    }
}

// ---------------- SAGE layer 0: h' = LN(h + relu(agg@WL + bl + h@WR)) -> hb, h8 ----------------
__global__ __launch_bounds__(256) void k_sage0(
    const u16* __restrict__ agg, const u16* __restrict__ hb,
    const u16* __restrict__ WTl, const u16* __restrict__ WTr,
    const float* __restrict__ bl, const float* __restrict__ lg,
    const float* __restrict__ lb, u16* __restrict__ hb_out,
    unsigned char* __restrict__ h8) {
  __shared__ u16 lds[32768];
  u16* wl = lds;
  u16* wr = lds + 16384;
  const int tid = threadIdx.x;
  const int wv = tid >> 6, ln = tid & 63;
  const int lrow = ln & 15, kg = ln >> 4;
  const int tbase = blockIdx.x * 128 + wv * 32;
  const int ar0 = min(tbase + lrow, NN - 1);
  const int ar1 = min(tbase + 16 + lrow, NN - 1);

  stage<2048>(WTl, wl, tid);
  stage<2048>(WTr, wr, tid);
  __syncthreads();

  f32x4 acc0[8], acc1[8];
#pragma unroll
  for (int cf = 0; cf < 8; ++cf) {
    acc0[cf] = (f32x4){0.f, 0.f, 0.f, 0.f};
    acc1[cf] = (f32x4){0.f, 0.f, 0.f, 0.f};
  }
#pragma unroll
  for (int ks = 0; ks < 4; ++ks) {
    const s16x8 g0 = *reinterpret_cast<const s16x8*>(agg + (size_t)ar0 * 128 + ks * 32 + kg * 8);
    const s16x8 g1 = *reinterpret_cast<const s16x8*>(agg + (size_t)ar1 * 128 + ks * 32 + kg * 8);
    const s16x8 h0 = *reinterpret_cast<const s16x8*>(hb + (size_t)ar0 * 128 + ks * 32 + kg * 8);
    const s16x8 h1 = *reinterpret_cast<const s16x8*>(hb + (size_t)ar1 * 128 + ks * 32 + kg * 8);
#pragma unroll
    for (int cf = 0; cf < 8; ++cf) {
      const s16x8 bwl = ldsw(wl, cf * 16 + lrow, ks * 4 + kg);
      const s16x8 bwr = ldsw(wr, cf * 16 + lrow, ks * 4 + kg);
      acc0[cf] = __builtin_amdgcn_mfma_f32_16x16x32_bf16(g0, bwl, acc0[cf], 0, 0, 0);
      acc0[cf] = __builtin_amdgcn_mfma_f32_16x16x32_bf16(h0, bwr, acc0[cf], 0, 0, 0);
      acc1[cf] = __builtin_amdgcn_mfma_f32_16x16x32_bf16(g1, bwl, acc1[cf], 0, 0, 0);
      acc1[cf] = __builtin_amdgcn_mfma_f32_16x16x32_bf16(h1, bwr, acc1[cf], 0, 0, 0);
    }
  }

  float bb[8], gm[8], gb[8];
#pragma unroll
  for (int cf = 0; cf < 8; ++cf) {
    const int c = cf * 16 + lrow;
    bb[cf] = bl[c];
    gm[cf] = lg[c];
    gb[cf] = lb[c];
  }
#pragma unroll
  for (int t = 0; t < 2; ++t)
#pragma unroll
    for (int j = 0; j < 4; ++j) {
      const int r = tbase + t * 16 + kg * 4 + j;
      const int rs = r < NN ? r : NN - 1;
      float v[8];
#pragma unroll
      for (int cf = 0; cf < 8; ++cf) {
        const int c = cf * 16 + lrow;
        v[cf] = b2f(hb[(size_t)rs * 128 + c]) +
                fmaxf((t ? acc1[cf][j] : acc0[cf][j]) + bb[cf], 0.0f);
      }
      float s = 0.f;
#pragma unroll
      for (int cf = 0; cf < 8; ++cf) s += v[cf];
      s += __shfl_xor(s, 1); s += __shfl_xor(s, 2);
      s += __shfl_xor(s, 4); s += __shfl_xor(s, 8);
      const float mu = s * (1.0f / 128);
      float q = 0.f;
#pragma unroll
      for (int cf = 0; cf < 8; ++cf) { const float d = v[cf] - mu; q += d * d; }
      q += __shfl_xor(q, 1); q += __shfl_xor(q, 2);
      q += __shfl_xor(q, 4); q += __shfl_xor(q, 8);
      const float istd = rsqrtf(q * (1.0f / 128) + 1e-5f);
      if (r < NN) {
        float ov[8];
#pragma unroll
        for (int cf = 0; cf < 8; ++cf) {
          ov[cf] = (v[cf] - mu) * istd * gm[cf] + gb[cf];
          hb_out[(size_t)r * 128 + cf * 16 + lrow] = f2b(ov[cf]);
        }
        *reinterpret_cast<uint2*>(&h8[(size_t)r * 128 + lrow * 8]) = pack_fp8(ov);
      }
    }
}

// ---------------- SAGE layer 1 + classifier fused ----------------
// LDS: [0,16384)=WTl -> th tile; [16384,32768)=WTr -> Wc1; [32768,37888)=Wc2
__global__ __launch_bounds__(256) void k_sage_cls(
    const u16* __restrict__ agg, const u16* __restrict__ hb,
    const u16* __restrict__ WTl, const u16* __restrict__ WTr,
    const float* __restrict__ bl, const float* __restrict__ lg,
    const float* __restrict__ lb,
    const u16* __restrict__ Wc1, const float* __restrict__ cb1,
    const u16* __restrict__ Wc2, const float* __restrict__ cb2,
    float* __restrict__ out_h, float* __restrict__ logits) {
  __shared__ u16 lds[37888];
  u16* wl = lds;          // phase A: WTl ; phase B: th tile (128x128)
  u16* wr = lds + 16384;  // phase A: WTr ; phase B: Wc1
  u16* w2 = lds + 32768;  // Wc2 (40x128)
  const int tid = threadIdx.x;
  const int wv = tid >> 6, ln = tid & 63;
  const int lrow = ln & 15, kg = ln >> 4;
  const int tbase = blockIdx.x * 128 + wv * 32;
  const int lb0 = wv * 32;
  const int ar0 = min(tbase + lrow, NN - 1);
  const int ar1 = min(tbase + 16 + lrow, NN - 1);

  stage<2048>(WTl, wl, tid);
  stage<2048>(WTr, wr, tid);
  stage<640>(Wc2, w2, tid);
  __syncthreads();

  f32x4 acc0[8], acc1[8];
#pragma unroll
  for (int cf = 0; cf < 8; ++cf) {
    acc0[cf] = (f32x4){0.f, 0.f, 0.f, 0.f};
    acc1[cf] = (f32x4){0.f, 0.f, 0.f, 0.f};
  }
#pragma unroll
  for (int ks = 0; ks < 4; ++ks) {
    const s16x8 g0 = *reinterpret_cast<const s16x8*>(agg + (size_t)ar0 * 128 + ks * 32 + kg * 8);
    const s16x8 g1 = *reinterpret_cast<const s16x8*>(agg + (size_t)ar1 * 128 + ks * 32 + kg * 8);
    const s16x8 h0 = *reinterpret_cast<const s16x8*>(hb + (size_t)ar0 * 128 + ks * 32 + kg * 8);
    const s16x8 h1 = *reinterpret_cast<const s16x8*>(hb + (size_t)ar1 * 128 + ks * 32 + kg * 8);
#pragma unroll
    for (int cf = 0; cf < 8; ++cf) {
      const s16x8 bwl = ldsw(wl, cf * 16 + lrow, ks * 4 + kg);
      const s16x8 bwr = ldsw(wr, cf * 16 + lrow, ks * 4 + kg);
      acc0[cf] = __builtin_amdgcn_mfma_f32_16x16x32_bf16(g0, bwl, acc0[cf], 0, 0, 0);
      acc0[cf] = __builtin_amdgcn_mfma_f32_16x16x32_bf16(h0, bwr, acc0[cf], 0, 0, 0);
      acc1[cf] = __builtin_amdgcn_mfma_f32_16x16x32_bf16(g1, bwl, acc1[cf], 0, 0, 0);
      acc1[cf] = __builtin_amdgcn_mfma_f32_16x16x32_bf16(h1, bwr, acc1[cf], 0, 0, 0);
    }
  }
  __syncthreads();  // all waves done reading WTl/WTr

  {
    float bb[8], gm[8], gb[8];
#pragma unroll
    for (int cf = 0; cf < 8; ++cf) {
      const int c = cf * 16 + lrow;
      bb[cf] = bl[c];
      gm[cf] = lg[c];
      gb[cf] = lb[c];
    }
#pragma unroll
    for (int t = 0; t < 2; ++t)
#pragma unroll
      for (int j = 0; j < 4; ++j) {
        const int r = tbase + t * 16 + kg * 4 + j;
        const int rs = r < NN ? r : NN - 1;
        const int lr = lb0 + t * 16 + kg * 4 + j;
        float v[8];
#pragma unroll
        for (int cf = 0; cf < 8; ++cf) {
          const int c = cf * 16 + lrow;
          v[cf] = b2f(hb[(size_t)rs * 128 + c]) +
                  fmaxf((t ? acc1[cf][j] : acc0[cf][j]) + bb[cf], 0.0f);
        }
        float s = 0.f;
#pragma unroll
        for (int cf = 0; cf < 8; ++cf) s += v[cf];
        s += __shfl_xor(s, 1); s += __shfl_xor(s, 2);
        s += __shfl_xor(s, 4); s += __shfl_xor(s, 8);
        const float mu = s * (1.0f / 128);
        float q = 0.f;
#pragma unroll
        for (int cf = 0; cf < 8; ++cf) { const float d = v[cf] - mu; q += d * d; }
        q += __shfl_xor(q, 1); q += __shfl_xor(q, 2);
        q += __shfl_xor(q, 4); q += __shfl_xor(q, 8);
        const float istd = rsqrtf(q * (1.0f / 128) + 1e-5f);
#pragma unroll
        for (int cf = 0; cf < 8; ++cf) {
          const int c = cf * 16 + lrow;
          const float o = (v[cf] - mu) * istd * gm[cf] + gb[cf];
          stsw(wl, lr, c, f2b(o));
          if (r < NN) out_h[(size_t)r * 128 + c] = o;
        }
      }
  }
  stage<2048>(Wc1, wr, tid);  // Wc1 over WTr (all reads done at barrier above)
  __syncthreads();

  // classifier: per wave, its own two 16-row th tiles
  float cb1v[8];
#pragma unroll
  for (int cf = 0; cf < 8; ++cf) cb1v[cf] = cb1[cf * 16 + lrow];

#pragma unroll
  for (int t = 0; t < 2; ++t) {
    const int rb = lb0 + t * 16;
    f32x4 a3[8];
#pragma unroll
    for (int cf = 0; cf < 8; ++cf) a3[cf] = (f32x4){0.f, 0.f, 0.f, 0.f};
#pragma unroll
    for (int ks = 0; ks < 4; ++ks) {
      const s16x8 a = ldsw(wl, rb + lrow, ks * 4 + kg);
#pragma unroll
      for (int cf = 0; cf < 8; ++cf) {
        const s16x8 bf = ldsw(wr, cf * 16 + lrow, ks * 4 + kg);
        a3[cf] = __builtin_amdgcn_mfma_f32_16x16x32_bf16(a, bf, a3[cf], 0, 0, 0);
      }
    }
    // t3 overwrites this wave's own th rows
#pragma unroll
    for (int j = 0; j < 4; ++j)
#pragma unroll
      for (int cf = 0; cf < 8; ++cf)
        stsw(wl, rb + kg * 4 + j, cf * 16 + lrow, f2b(fmaxf(a3[cf][j] + cb1v[cf], 0.0f)));

    f32x4 a2[3];
#pragma unroll
    for (int cf = 0; cf < 3; ++cf) a2[cf] = (f32x4){0.f, 0.f, 0.f, 0.f};
#pragma unroll
    for (int ks = 0; ks < 4; ++ks) {
      const s16x8 a = ldsw(wl, rb + lrow, ks * 4 + kg);
#pragma unroll
      for (int cf = 0; cf < 3; ++cf) {
        const int bn = min(cf * 16 + lrow, CC - 1);
        const s16x8 bf = ldsw(w2, bn, ks * 4 + kg);
        a2[cf] = __builtin_amdgcn_mfma_f32_16x16x32_bf16(a, bf, a2[cf], 0, 0, 0);
      }
    }
#pragma unroll
    for (int j = 0; j < 4; ++j) {
      const int r = tbase + t * 16 + kg * 4 + j;
      if (r < NN) {
#pragma unroll
        for (int cf = 0; cf < 3; ++cf) {
          const int c = cf * 16 + lrow;
          if (c < CC) logits[(size_t)r * CC + c] = a2[cf][j] + cb2[c];
        }
      }
    }
  }
}

}  // namespace

extern "C" void kernel_launch(void* const* d_in, const int* in_sizes, int n_in,
                              void* d_out, int out_size, void* d_ws, size_t ws_size,
                              hipStream_t stream) {
  (void)in_sizes; (void)n_in; (void)out_size; (void)ws_size;
  const float* x   = (const float*)d_in[0];
  const int*   ei  = (const int*)d_in[1];
  const float* pw1 = (const float*)d_in[2];
  const float* pb1 = (const float*)d_in[3];
  const float* pw2 = (const float*)d_in[4];
  const float* pb2 = (const float*)d_in[5];
  const float* ing = (const float*)d_in[6];
  const float* inb = (const float*)d_in[7];
  const float* swl = (const float*)d_in[8];
  const float* sbl = (const float*)d_in[9];
  const float* swr = (const float*)d_in[10];
  const float* lng = (const float*)d_in[11];
  const float* lnb = (const float*)d_in[12];
  const float* cw1 = (const float*)d_in[13];
  const float* cb1 = (const float*)d_in[14];
  const float* cw2 = (const float*)d_in[15];
  const float* cb2 = (const float*)d_in[16];

  float* out_logits = (float*)d_out;
  float* out_h = out_logits + (size_t)NN * CC;

  const size_t NNH = (size_t)NN * HH;
  u16*   hb   = (u16*)d_ws;                // 12.8 MB
  u16*   bufA = hb + NNH;                  // 12.8 MB (agg)
  u16*   wt   = bufA + NNH;                // 256 KB
  int*   cnt    = (int*)(wt + 8 * 16384);  // NN
  float* inv    = (float*)(cnt + NN);      // NN
  int*   rowptr = (int*)(inv + NN);        // NN+1
  int*   bsum   = rowptr + NN + 1;         // 256
  int*   colarr = bsum + 256;              // EE
  int*   rankar = colarr + EE;             // EE
  unsigned char* h8 = (unsigned char*)(rankar + EE);  // NN*128 bytes (fp8)

  // ---- prelude: WT1/WT2 transpose + cnt zero ----
  const int PRE_B = (2 * 16384 + NN + 255) / 256;
  k_pre<<<PRE_B, 256, 0, stream>>>(pw1, pw2, wt, cnt);

  // ---- input MLP with degree histogram + sage/cls weight-prep ridden in ----
  k_mlp_deg<<<MG + DEGB + WPB, 256, 0, stream>>>(
      x, wt + 0 * 16384, pb1, wt + 1 * 16384, pb2, ing, inb, hb, h8,
      ei, cnt, rankar, swl, swr, cw1, cw2, wt);

  // ---- CSR scan + atomic-free fill ----
  k_scan_block<<<SCAN_NB, 256, 0, stream>>>(cnt, rowptr, bsum, inv);
  k_scan_add<<<SCAN_NB, 256, 0, stream>>>(rowptr, bsum);
  k_fill<<<(EE + 255) / 256, 256, 0, stream>>>(ei, rowptr, rankar, colarr);

  // layer 0 (fp8 gather)
  k_gather8<<<(NN + 15) / 16, 256, 0, stream>>>(h8, rowptr, colarr, inv, bufA);
  k_sage0<<<(NN + 127) / 128, 256, 0, stream>>>(
      bufA, hb, wt + 2 * 16384, wt + 4 * 16384, sbl, lng, lnb, hb, h8);

  // layer 1 + classifier
  k_gather8<<<(NN + 15) / 16, 256, 0, stream>>>(h8, rowptr, colarr, inv, bufA);
  k_sage_cls<<<(NN + 127) / 128, 256, 0, stream>>>(
      bufA, hb, wt + 3 * 16384, wt + 5 * 16384, sbl + HH, lng + HH, lnb + HH,
      wt + 6 * 16384, cb1, wt + 7 * 16384, cb2, out_h, out_logits);
}

// Round 16
// 138.469 us; speedup vs baseline: 1.0788x; 1.0311x over previous
//
#include <hip/hip_runtime.h>

// GNN encoder: input MLP + LN, 2x SAGEConv(mean) + ReLU + residual + LN, classifier MLP.
// Round 16 (base = round 15 / best 142.8us): CSR tail consolidation.
//  - k_scanfill: scan_add (finalize rpf for gather) + edge fill merged in one dispatch;
//    fill blocks compute the 196-entry bsum prefix locally (no dependence on scan_add).
//  - col[] stored as u16 (node ids < 65536): halves fill payload + gather col stream.
// Everything else identical to round 15.

namespace {

constexpr int NN = 50000;
constexpr int EE = 640000;
constexpr int HH = 128;
constexpr int CC = 40;
constexpr int SCAN_NB = (NN + 255) / 256;  // 196
constexpr int MG = (NN + 127) / 128;       // 391 (mlp blocks)
constexpr int DEGB = (EE + 255) / 256;     // 2500 (degree blocks)
constexpr int WPB = (5 * 16384 + CC * 128 + 255) / 256;  // 340 (wt slots 2..7)
constexpr int FILLB = (EE + 255) / 256;    // 2500 (fill blocks)

typedef unsigned short u16;
typedef __attribute__((ext_vector_type(8))) short s16x8;
typedef __attribute__((ext_vector_type(8))) unsigned short u16x8;
typedef __attribute__((ext_vector_type(4))) float f32x4;
typedef __attribute__((ext_vector_type(2))) float f32x2;

__device__ __forceinline__ float b2f(u16 h) {
  unsigned int u = ((unsigned int)h) << 16;
  return __builtin_bit_cast(float, u);
}
__device__ __forceinline__ u16 f2b(float f) {
  unsigned int u = __builtin_bit_cast(unsigned int, f);
  u += 0x7FFFu + ((u >> 16) & 1u);
  return (u16)(u >> 16);
}

// pack 8 floats -> 8 fp8 e4m3 bytes (v[q] -> byte q)
__device__ __forceinline__ uint2 pack_fp8(const float* v) {
  int w0 = 0, w1 = 0;
  w0 = __builtin_amdgcn_cvt_pk_fp8_f32(v[0], v[1], w0, false);
  w0 = __builtin_amdgcn_cvt_pk_fp8_f32(v[2], v[3], w0, true);
  w1 = __builtin_amdgcn_cvt_pk_fp8_f32(v[4], v[5], w1, false);
  w1 = __builtin_amdgcn_cvt_pk_fp8_f32(v[6], v[7], w1, true);
  return make_uint2((unsigned)w0, (unsigned)w1);
}
// accumulate 8 fp8 bytes into a[0..7]
__device__ __forceinline__ void acc_fp8(float* a, uint2 p) {
  const f32x2 f0 = __builtin_amdgcn_cvt_pk_f32_fp8((int)p.x, false);
  const f32x2 f1 = __builtin_amdgcn_cvt_pk_f32_fp8((int)p.x, true);
  const f32x2 f2 = __builtin_amdgcn_cvt_pk_f32_fp8((int)p.y, false);
  const f32x2 f3 = __builtin_amdgcn_cvt_pk_f32_fp8((int)p.y, true);
  a[0] += f0.x; a[1] += f0.y; a[2] += f1.x; a[3] += f1.y;
  a[4] += f2.x; a[5] += f2.y; a[6] += f3.x; a[7] += f3.y;
}

// ---- swizzled LDS tile: row n, 16B-granule k0; slot = k0 ^ (n&15) ----
__device__ __forceinline__ s16x8 ldsw(const u16* base, int n, int k0) {
  return *reinterpret_cast<const s16x8*>(base + n * 128 + (((k0 ^ n) & 15) << 3));
}
__device__ __forceinline__ void stsw(u16* base, int r, int c, u16 v) {
  base[r * 128 + ((((c >> 3) ^ r) & 15) << 3) + (c & 7)] = v;
}
template <int NGRAN>
__device__ __forceinline__ void stage(const u16* __restrict__ src, u16* dst, int tid) {
#pragma unroll
  for (int i = 0; i < (NGRAN + 255) / 256; ++i) {
    const int gi = i * 256 + tid;
    if ((NGRAN & 255) == 0 || gi < NGRAN) {
      const int n = gi >> 4, k0 = gi & 15;
      const u16x8 v = *reinterpret_cast<const u16x8*>(src + gi * 8);
      *reinterpret_cast<u16x8*>(dst + n * 128 + (((k0 ^ n) & 15) << 3)) = v;
    }
  }
}

// ---------------- prelude: WT1/WT2 transpose + cnt zero ----------------
__global__ void k_pre(const float* __restrict__ pw1, const float* __restrict__ pw2,
                      u16* __restrict__ wt, int* __restrict__ cnt) {
  int flat = blockIdx.x * 256 + threadIdx.x;
  const int TWO = 2 * 16384;
  if (flat < TWO) {
    int id = flat >> 14;
    int off = flat & 16383;
    int n = off >> 7, k = off & 127;
    const float* s = id == 0 ? pw1 : pw2;
    wt[(size_t)id * 16384 + n * 128 + k] = f2b(s[k * 128 + n]);
  } else {
    int i = flat - TWO;
    if (i < NN) cnt[i] = 0;
  }
}

// ---------------- CSR scan phase 1: per-block exclusive scan + bsum + inv ----------------
__global__ void k_scan_block(const int* __restrict__ cnt, int* __restrict__ rloc,
                             int* __restrict__ bsum, float* __restrict__ inv) {
  __shared__ int s[256];
  const int t = threadIdx.x;
  const int i = blockIdx.x * 256 + t;
  const int v = i < NN ? cnt[i] : 0;
  s[t] = v;
  __syncthreads();
  for (int off = 1; off < 256; off <<= 1) {
    int add = t >= off ? s[t - off] : 0;
    __syncthreads();
    s[t] += add;
    __syncthreads();
  }
  if (i < NN) {
    rloc[i] = s[t] - v;  // exclusive within block
    inv[i] = v > 0 ? 1.0f / (float)v : 0.0f;
  }
  if (t == 255) bsum[blockIdx.x] = s[255];
}

// ---------------- merged: finalize rpf (for gather) AND fill col (u16) ----------------
// All blocks locally scan the 196 block sums in LDS, then:
//  blocks [0,SCAN_NB):  rpf[i] = rloc[i] + prefix;  rpf[NN] = EE
//  blocks [SCAN_NB, ..): col[rloc[d] + prefix(block(d)) + rank[e]] = (u16)src
__global__ void k_scanfill(const int* __restrict__ rloc, const int* __restrict__ bsum,
                           int* __restrict__ rpf,
                           const int* __restrict__ ei, const int* __restrict__ rank,
                           u16* __restrict__ col) {
  __shared__ int s[256];
  const int t = threadIdx.x;
  {
    const int v = t < SCAN_NB ? bsum[t] : 0;
    s[t] = v;
    __syncthreads();
    for (int off = 1; off < 256; off <<= 1) {
      int add = t >= off ? s[t - off] : 0;
      __syncthreads();
      s[t] += add;
      __syncthreads();
    }
  }
  if (blockIdx.x < SCAN_NB) {
    const int boff = blockIdx.x == 0 ? 0 : s[blockIdx.x - 1];
    const int i = blockIdx.x * 256 + t;
    if (i < NN) rpf[i] = rloc[i] + boff;
    if (i == 0) rpf[NN] = EE;
  } else {
    const int e = (blockIdx.x - SCAN_NB) * 256 + t;
    if (e < EE) {
      const int d = ei[EE + e];
      const int bd = d >> 8;
      const int boff = bd == 0 ? 0 : s[bd - 1];
      col[rloc[d] + boff + rank[e]] = (u16)ei[e];
    }
  }
}

// ---------------- aggregation: fp8 reads, quarter-wave per node, 8 in flight ----------------
__global__ __launch_bounds__(256) void k_gather8(
    const unsigned char* __restrict__ h8, const int* __restrict__ rowptr,
    const u16* __restrict__ col, const float* __restrict__ inv,
    u16* __restrict__ agg) {
  const int tid = threadIdx.x;
  const int node = blockIdx.x * 16 + (tid >> 4);
  if (node >= NN) return;
  const int ln = tid & 15;
  const int cl = ln * 8;
  const int start = rowptr[node];
  const int end = rowptr[node + 1];
  float a[8] = {0.f, 0.f, 0.f, 0.f, 0.f, 0.f, 0.f, 0.f};
  int i = start;
  for (; i + 8 <= end; i += 8) {
    const int s0 = col[i], s1 = col[i + 1], s2 = col[i + 2], s3 = col[i + 3];
    const int s4 = col[i + 4], s5 = col[i + 5], s6 = col[i + 6], s7 = col[i + 7];
    const uint2 p0 = *reinterpret_cast<const uint2*>(&h8[(size_t)s0 * 128 + cl]);
    const uint2 p1 = *reinterpret_cast<const uint2*>(&h8[(size_t)s1 * 128 + cl]);
    const uint2 p2 = *reinterpret_cast<const uint2*>(&h8[(size_t)s2 * 128 + cl]);
    const uint2 p3 = *reinterpret_cast<const uint2*>(&h8[(size_t)s3 * 128 + cl]);
    const uint2 p4 = *reinterpret_cast<const uint2*>(&h8[(size_t)s4 * 128 + cl]);
    const uint2 p5 = *reinterpret_cast<const uint2*>(&h8[(size_t)s5 * 128 + cl]);
    const uint2 p6 = *reinterpret_cast<const uint2*>(&h8[(size_t)s6 * 128 + cl]);
    const uint2 p7 = *reinterpret_cast<const uint2*>(&h8[(size_t)s7 * 128 + cl]);
    acc_fp8(a, p0); acc_fp8(a, p1); acc_fp8(a, p2); acc_fp8(a, p3);
    acc_fp8(a, p4); acc_fp8(a, p5); acc_fp8(a, p6); acc_fp8(a, p7);
  }
  if (i + 4 <= end) {
    const int s0 = col[i], s1 = col[i + 1], s2 = col[i + 2], s3 = col[i + 3];
    const uint2 p0 = *reinterpret_cast<const uint2*>(&h8[(size_t)s0 * 128 + cl]);
    const uint2 p1 = *reinterpret_cast<const uint2*>(&h8[(size_t)s1 * 128 + cl]);
    const uint2 p2 = *reinterpret_cast<const uint2*>(&h8[(size_t)s2 * 128 + cl]);
    const uint2 p3 = *reinterpret_cast<const uint2*>(&h8[(size_t)s3 * 128 + cl]);
    acc_fp8(a, p0); acc_fp8(a, p1); acc_fp8(a, p2); acc_fp8(a, p3);
    i += 4;
  }
  for (; i < end; ++i) {
    const uint2 p0 = *reinterpret_cast<const uint2*>(&h8[(size_t)col[i] * 128 + cl]);
    acc_fp8(a, p0);
  }
  const float sc = inv[node];
  // a[k] corresponds to real column k*16 + ln (permuted h8 layout)
#pragma unroll
  for (int k = 0; k < 8; ++k)
    agg[(size_t)node * 128 + k * 16 + ln] = f2b(a[k] * sc);
}

// ---------------- fused input MLP + riders (degree, wt slots 2..7) ----------------
__global__ __launch_bounds__(256) void k_mlp_deg(
    const float* __restrict__ x, const u16* __restrict__ WT1,
    const float* __restrict__ pb1, const u16* __restrict__ WT2,
    const float* __restrict__ pb2, const float* __restrict__ lg,
    const float* __restrict__ lb, u16* __restrict__ hb,
    unsigned char* __restrict__ h8,
    const int* __restrict__ ei, int* __restrict__ cnt, int* __restrict__ rank,
    const float* __restrict__ swl, const float* __restrict__ swr,
    const float* __restrict__ cw1, const float* __restrict__ cw2,
    u16* __restrict__ wt) {
  __shared__ u16 lds[32768];
  if (blockIdx.x >= MG) {
    const int rb = blockIdx.x - MG;
    if (rb < DEGB) {
      const int e = rb * 256 + threadIdx.x;
      if (e < EE) rank[e] = atomicAdd(&cnt[ei[EE + e]], 1);
    } else {
      const int flat = (rb - DEGB) * 256 + threadIdx.x;
      const int FIVE = 5 * 16384;
      if (flat < FIVE) {
        int id = flat >> 14;  // 0..4 -> slots 2..6
        int off = flat & 16383;
        int n = off >> 7, k = off & 127;
        const float* s;
        switch (id) {
          case 0: s = swl; break;
          case 1: s = swl + 16384; break;
          case 2: s = swr; break;
          case 3: s = swr + 16384; break;
          default: s = cw1; break;
        }
        wt[(size_t)(id + 2) * 16384 + n * 128 + k] = f2b(s[k * 128 + n]);
      } else {
        int off = flat - FIVE;
        if (off < CC * 128) {
          int n = off >> 7, k = off & 127;
          wt[(size_t)7 * 16384 + n * 128 + k] = f2b(cw2[k * CC + n]);
        }
      }
    }
    return;
  }
  u16* wreg = lds;
  u16* t1r = lds + 16384;
  const int tid = threadIdx.x;
  const int wv = tid >> 6, ln = tid & 63;
  const int lrow = ln & 15, kg = ln >> 4;
  const int tbase = blockIdx.x * 128 + wv * 32;
  const int lb0 = wv * 32;
  const int ar0 = min(tbase + lrow, NN - 1);
  const int ar1 = min(tbase + 16 + lrow, NN - 1);

  stage<2048>(WT1, wreg, tid);
  __syncthreads();

  f32x4 acc0[8], acc1[8];
#pragma unroll
  for (int cf = 0; cf < 8; ++cf) {
    acc0[cf] = (f32x4){0.f, 0.f, 0.f, 0.f};
    acc1[cf] = (f32x4){0.f, 0.f, 0.f, 0.f};
  }
#pragma unroll
  for (int ks = 0; ks < 4; ++ks) {
    const float4* p0 = reinterpret_cast<const float4*>(x + (size_t)ar0 * 128 + ks * 32 + kg * 8);
    const float4* p1 = reinterpret_cast<const float4*>(x + (size_t)ar1 * 128 + ks * 32 + kg * 8);
    float4 x0 = p0[0], x1 = p0[1], y0 = p1[0], y1 = p1[1];
    s16x8 a0, a1;
    a0[0] = (short)f2b(x0.x); a0[1] = (short)f2b(x0.y); a0[2] = (short)f2b(x0.z); a0[3] = (short)f2b(x0.w);
    a0[4] = (short)f2b(x1.x); a0[5] = (short)f2b(x1.y); a0[6] = (short)f2b(x1.z); a0[7] = (short)f2b(x1.w);
    a1[0] = (short)f2b(y0.x); a1[1] = (short)f2b(y0.y); a1[2] = (short)f2b(y0.z); a1[3] = (short)f2b(y0.w);
    a1[4] = (short)f2b(y1.x); a1[5] = (short)f2b(y1.y); a1[6] = (short)f2b(y1.z); a1[7] = (short)f2b(y1.w);
#pragma unroll
    for (int cf = 0; cf < 8; ++cf) {
      const s16x8 bf = ldsw(wreg, cf * 16 + lrow, ks * 4 + kg);
      acc0[cf] = __builtin_amdgcn_mfma_f32_16x16x32_bf16(a0, bf, acc0[cf], 0, 0, 0);
      acc1[cf] = __builtin_amdgcn_mfma_f32_16x16x32_bf16(a1, bf, acc1[cf], 0, 0, 0);
    }
  }
  {
    float bb[8];
#pragma unroll
    for (int cf = 0; cf < 8; ++cf) bb[cf] = pb1[cf * 16 + lrow];
#pragma unroll
    for (int t = 0; t < 2; ++t)
#pragma unroll
      for (int j = 0; j < 4; ++j) {
        const int lr = lb0 + t * 16 + kg * 4 + j;
#pragma unroll
        for (int cf = 0; cf < 8; ++cf)
          stsw(t1r, lr, cf * 16 + lrow, f2b(fmaxf((t ? acc1[cf][j] : acc0[cf][j]) + bb[cf], 0.0f)));
      }
  }
  __syncthreads();
  stage<2048>(WT2, wreg, tid);
  __syncthreads();

  f32x4 c0[8], c1[8];
#pragma unroll
  for (int cf = 0; cf < 8; ++cf) {
    c0[cf] = (f32x4){0.f, 0.f, 0.f, 0.f};
    c1[cf] = (f32x4){0.f, 0.f, 0.f, 0.f};
  }
#pragma unroll
  for (int ks = 0; ks < 4; ++ks) {
    const s16x8 a0 = ldsw(t1r, lb0 + lrow, ks * 4 + kg);
    const s16x8 a1 = ldsw(t1r, lb0 + 16 + lrow, ks * 4 + kg);
#pragma unroll
    for (int cf = 0; cf < 8; ++cf) {
      const s16x8 bf = ldsw(wreg, cf * 16 + lrow, ks * 4 + kg);
      c0[cf] = __builtin_amdgcn_mfma_f32_16x16x32_bf16(a0, bf, c0[cf], 0, 0, 0);
      c1[cf] = __builtin_amdgcn_mfma_f32_16x16x32_bf16(a1, bf, c1[cf], 0, 0, 0);
    }
  }

  float bb[8], gm[8], gb[8];
#pragma unroll
  for (int cf = 0; cf < 8; ++cf) {
    const int c = cf * 16 + lrow;
    bb[cf] = pb2[c];
    gm[cf] = lg[c];
    gb[cf] = lb[c];
  }
#pragma unroll
  for (int t = 0; t < 2; ++t)
#pragma unroll
    for (int j = 0; j < 4; ++j) {
      const int r = tbase + t * 16 + kg * 4 + j;
      float v[8];
#pragma unroll
      for (int cf = 0; cf < 8; ++cf) v[cf] = (t ? c1[cf][j] : c0[cf][j]) + bb[cf];
      float s = 0.f;
#pragma unroll
      for (int cf = 0; cf < 8; ++cf) s += v[cf];
      s += __shfl_xor(s, 1); s += __shfl_xor(s, 2);
      s += __shfl_xor(s, 4); s += __shfl_xor(s, 8);
      const float mu = s * (1.0f / 128);
      float q = 0.f;
#pragma unroll
      for (int cf = 0; cf < 8; ++cf) { const float d = v[cf] - mu; q += d * d; }
      q += __shfl_xor(q, 1); q += __shfl_xor(q, 2);
      q += __shfl_xor(q, 4); q += __shfl_xor(q, 8);
      const float istd = rsqrtf(q * (1.0f / 128) + 1e-5f);
      if (r < NN) {
        float ov[8];
#pragma unroll
        for (int cf = 0; cf < 8; ++cf) {
          ov[cf] = (v[cf] - mu) * istd * gm[cf] + gb[cf];
          hb[(size_t)r * 128 + cf * 16 + lrow] = f2b(ov[cf]);
        }
        *reinterpret_cast<uint2*>(&h8[(size_t)r * 128 + lrow * 8]) = pack_fp8(ov);
      }
    }
}

// ---------------- SAGE layer 0: h' = LN(h + relu(agg@WL + bl + h@WR)) -> hb, h8 ----------------
__global__ __launch_bounds__(256) void k_sage0(
    const u16* __restrict__ agg, const u16* __restrict__ hb,
    const u16* __restrict__ WTl, const u16* __restrict__ WTr,
    const float* __restrict__ bl, const float* __restrict__ lg,
    const float* __restrict__ lb, u16* __restrict__ hb_out,
    unsigned char* __restrict__ h8) {
  __shared__ u16 lds[32768];
  u16* wl = lds;
  u16* wr = lds + 16384;
  const int tid = threadIdx.x;
  const int wv = tid >> 6, ln = tid & 63;
  const int lrow = ln & 15, kg = ln >> 4;
  const int tbase = blockIdx.x * 128 + wv * 32;
  const int ar0 = min(tbase + lrow, NN - 1);
  const int ar1 = min(tbase + 16 + lrow, NN - 1);

  stage<2048>(WTl, wl, tid);
  stage<2048>(WTr, wr, tid);
  __syncthreads();

  f32x4 acc0[8], acc1[8];
#pragma unroll
  for (int cf = 0; cf < 8; ++cf) {
    acc0[cf] = (f32x4){0.f, 0.f, 0.f, 0.f};
    acc1[cf] = (f32x4){0.f, 0.f, 0.f, 0.f};
  }
#pragma unroll
  for (int ks = 0; ks < 4; ++ks) {
    const s16x8 g0 = *reinterpret_cast<const s16x8*>(agg + (size_t)ar0 * 128 + ks * 32 + kg * 8);
    const s16x8 g1 = *reinterpret_cast<const s16x8*>(agg + (size_t)ar1 * 128 + ks * 32 + kg * 8);
    const s16x8 h0 = *reinterpret_cast<const s16x8*>(hb + (size_t)ar0 * 128 + ks * 32 + kg * 8);
    const s16x8 h1 = *reinterpret_cast<const s16x8*>(hb + (size_t)ar1 * 128 + ks * 32 + kg * 8);
#pragma unroll
    for (int cf = 0; cf < 8; ++cf) {
      const s16x8 bwl = ldsw(wl, cf * 16 + lrow, ks * 4 + kg);
      const s16x8 bwr = ldsw(wr, cf * 16 + lrow, ks * 4 + kg);
      acc0[cf] = __builtin_amdgcn_mfma_f32_16x16x32_bf16(g0, bwl, acc0[cf], 0, 0, 0);
      acc0[cf] = __builtin_amdgcn_mfma_f32_16x16x32_bf16(h0, bwr, acc0[cf], 0, 0, 0);
      acc1[cf] = __builtin_amdgcn_mfma_f32_16x16x32_bf16(g1, bwl, acc1[cf], 0, 0, 0);
      acc1[cf] = __builtin_amdgcn_mfma_f32_16x16x32_bf16(h1, bwr, acc1[cf], 0, 0, 0);
    }
  }

  float bb[8], gm[8], gb[8];
#pragma unroll
  for (int cf = 0; cf < 8; ++cf) {
    const int c = cf * 16 + lrow;
    bb[cf] = bl[c];
    gm[cf] = lg[c];
    gb[cf] = lb[c];
  }
#pragma unroll
  for (int t = 0; t < 2; ++t)
#pragma unroll
    for (int j = 0; j < 4; ++j) {
      const int r = tbase + t * 16 + kg * 4 + j;
      const int rs = r < NN ? r : NN - 1;
      float v[8];
#pragma unroll
      for (int cf = 0; cf < 8; ++cf) {
        const int c = cf * 16 + lrow;
        v[cf] = b2f(hb[(size_t)rs * 128 + c]) +
                fmaxf((t ? acc1[cf][j] : acc0[cf][j]) + bb[cf], 0.0f);
      }
      float s = 0.f;
#pragma unroll
      for (int cf = 0; cf < 8; ++cf) s += v[cf];
      s += __shfl_xor(s, 1); s += __shfl_xor(s, 2);
      s += __shfl_xor(s, 4); s += __shfl_xor(s, 8);
      const float mu = s * (1.0f / 128);
      float q = 0.f;
#pragma unroll
      for (int cf = 0; cf < 8; ++cf) { const float d = v[cf] - mu; q += d * d; }
      q += __shfl_xor(q, 1); q += __shfl_xor(q, 2);
      q += __shfl_xor(q, 4); q += __shfl_xor(q, 8);
      const float istd = rsqrtf(q * (1.0f / 128) + 1e-5f);
      if (r < NN) {
        float ov[8];
#pragma unroll
        for (int cf = 0; cf < 8; ++cf) {
          ov[cf] = (v[cf] - mu) * istd * gm[cf] + gb[cf];
          hb_out[(size_t)r * 128 + cf * 16 + lrow] = f2b(ov[cf]);
        }
        *reinterpret_cast<uint2*>(&h8[(size_t)r * 128 + lrow * 8]) = pack_fp8(ov);
      }
    }
}

// ---------------- SAGE layer 1 + classifier fused ----------------
// LDS: [0,16384)=WTl -> th tile; [16384,32768)=WTr -> Wc1; [32768,37888)=Wc2
__global__ __launch_bounds__(256) void k_sage_cls(
    const u16* __restrict__ agg, const u16* __restrict__ hb,
    const u16* __restrict__ WTl, const u16* __restrict__ WTr,
    const float* __restrict__ bl, const float* __restrict__ lg,
    const float* __restrict__ lb,
    const u16* __restrict__ Wc1, const float* __restrict__ cb1,
    const u16* __restrict__ Wc2, const float* __restrict__ cb2,
    float* __restrict__ out_h, float* __restrict__ logits) {
  __shared__ u16 lds[37888];
  u16* wl = lds;          // phase A: WTl ; phase B: th tile (128x128)
  u16* wr = lds + 16384;  // phase A: WTr ; phase B: Wc1
  u16* w2 = lds + 32768;  // Wc2 (40x128)
  const int tid = threadIdx.x;
  const int wv = tid >> 6, ln = tid & 63;
  const int lrow = ln & 15, kg = ln >> 4;
  const int tbase = blockIdx.x * 128 + wv * 32;
  const int lb0 = wv * 32;
  const int ar0 = min(tbase + lrow, NN - 1);
  const int ar1 = min(tbase + 16 + lrow, NN - 1);

  stage<2048>(WTl, wl, tid);
  stage<2048>(WTr, wr, tid);
  stage<640>(Wc2, w2, tid);
  __syncthreads();

  f32x4 acc0[8], acc1[8];
#pragma unroll
  for (int cf = 0; cf < 8; ++cf) {
    acc0[cf] = (f32x4){0.f, 0.f, 0.f, 0.f};
    acc1[cf] = (f32x4){0.f, 0.f, 0.f, 0.f};
  }
#pragma unroll
  for (int ks = 0; ks < 4; ++ks) {
    const s16x8 g0 = *reinterpret_cast<const s16x8*>(agg + (size_t)ar0 * 128 + ks * 32 + kg * 8);
    const s16x8 g1 = *reinterpret_cast<const s16x8*>(agg + (size_t)ar1 * 128 + ks * 32 + kg * 8);
    const s16x8 h0 = *reinterpret_cast<const s16x8*>(hb + (size_t)ar0 * 128 + ks * 32 + kg * 8);
    const s16x8 h1 = *reinterpret_cast<const s16x8*>(hb + (size_t)ar1 * 128 + ks * 32 + kg * 8);
#pragma unroll
    for (int cf = 0; cf < 8; ++cf) {
      const s16x8 bwl = ldsw(wl, cf * 16 + lrow, ks * 4 + kg);
      const s16x8 bwr = ldsw(wr, cf * 16 + lrow, ks * 4 + kg);
      acc0[cf] = __builtin_amdgcn_mfma_f32_16x16x32_bf16(g0, bwl, acc0[cf], 0, 0, 0);
      acc0[cf] = __builtin_amdgcn_mfma_f32_16x16x32_bf16(h0, bwr, acc0[cf], 0, 0, 0);
      acc1[cf] = __builtin_amdgcn_mfma_f32_16x16x32_bf16(g1, bwl, acc1[cf], 0, 0, 0);
      acc1[cf] = __builtin_amdgcn_mfma_f32_16x16x32_bf16(h1, bwr, acc1[cf], 0, 0, 0);
    }
  }
  __syncthreads();  // all waves done reading WTl/WTr

  {
    float bb[8], gm[8], gb[8];
#pragma unroll
    for (int cf = 0; cf < 8; ++cf) {
      const int c = cf * 16 + lrow;
      bb[cf] = bl[c];
      gm[cf] = lg[c];
      gb[cf] = lb[c];
    }
#pragma unroll
    for (int t = 0; t < 2; ++t)
#pragma unroll
      for (int j = 0; j < 4; ++j) {
        const int r = tbase + t * 16 + kg * 4 + j;
        const int rs = r < NN ? r : NN - 1;
        const int lr = lb0 + t * 16 + kg * 4 + j;
        float v[8];
#pragma unroll
        for (int cf = 0; cf < 8; ++cf) {
          const int c = cf * 16 + lrow;
          v[cf] = b2f(hb[(size_t)rs * 128 + c]) +
                  fmaxf((t ? acc1[cf][j] : acc0[cf][j]) + bb[cf], 0.0f);
        }
        float s = 0.f;
#pragma unroll
        for (int cf = 0; cf < 8; ++cf) s += v[cf];
        s += __shfl_xor(s, 1); s += __shfl_xor(s, 2);
        s += __shfl_xor(s, 4); s += __shfl_xor(s, 8);
        const float mu = s * (1.0f / 128);
        float q = 0.f;
#pragma unroll
        for (int cf = 0; cf < 8; ++cf) { const float d = v[cf] - mu; q += d * d; }
        q += __shfl_xor(q, 1); q += __shfl_xor(q, 2);
        q += __shfl_xor(q, 4); q += __shfl_xor(q, 8);
        const float istd = rsqrtf(q * (1.0f / 128) + 1e-5f);
#pragma unroll
        for (int cf = 0; cf < 8; ++cf) {
          const int c = cf * 16 + lrow;
          const float o = (v[cf] - mu) * istd * gm[cf] + gb[cf];
          stsw(wl, lr, c, f2b(o));
          if (r < NN) out_h[(size_t)r * 128 + c] = o;
        }
      }
  }
  stage<2048>(Wc1, wr, tid);  // Wc1 over WTr (all reads done at barrier above)
  __syncthreads();

  // classifier: per wave, its own two 16-row th tiles
  float cb1v[8];
#pragma unroll
  for (int cf = 0; cf < 8; ++cf) cb1v[cf] = cb1[cf * 16 + lrow];

#pragma unroll
  for (int t = 0; t < 2; ++t) {
    const int rb = lb0 + t * 16;
    f32x4 a3[8];
#pragma unroll
    for (int cf = 0; cf < 8; ++cf) a3[cf] = (f32x4){0.f, 0.f, 0.f, 0.f};
#pragma unroll
    for (int ks = 0; ks < 4; ++ks) {
      const s16x8 a = ldsw(wl, rb + lrow, ks * 4 + kg);
#pragma unroll
      for (int cf = 0; cf < 8; ++cf) {
        const s16x8 bf = ldsw(wr, cf * 16 + lrow, ks * 4 + kg);
        a3[cf] = __builtin_amdgcn_mfma_f32_16x16x32_bf16(a, bf, a3[cf], 0, 0, 0);
      }
    }
    // t3 overwrites this wave's own th rows
#pragma unroll
    for (int j = 0; j < 4; ++j)
#pragma unroll
      for (int cf = 0; cf < 8; ++cf)
        stsw(wl, rb + kg * 4 + j, cf * 16 + lrow, f2b(fmaxf(a3[cf][j] + cb1v[cf], 0.0f)));

    f32x4 a2[3];
#pragma unroll
    for (int cf = 0; cf < 3; ++cf) a2[cf] = (f32x4){0.f, 0.f, 0.f, 0.f};
#pragma unroll
    for (int ks = 0; ks < 4; ++ks) {
      const s16x8 a = ldsw(wl, rb + lrow, ks * 4 + kg);
#pragma unroll
      for (int cf = 0; cf < 3; ++cf) {
        const int bn = min(cf * 16 + lrow, CC - 1);
        const s16x8 bf = ldsw(w2, bn, ks * 4 + kg);
        a2[cf] = __builtin_amdgcn_mfma_f32_16x16x32_bf16(a, bf, a2[cf], 0, 0, 0);
      }
    }
#pragma unroll
    for (int j = 0; j < 4; ++j) {
      const int r = tbase + t * 16 + kg * 4 + j;
      if (r < NN) {
#pragma unroll
        for (int cf = 0; cf < 3; ++cf) {
          const int c = cf * 16 + lrow;
          if (c < CC) logits[(size_t)r * CC + c] = a2[cf][j] + cb2[c];
        }
      }
    }
  }
}

}  // namespace

extern "C" void kernel_launch(void* const* d_in, const int* in_sizes, int n_in,
                              void* d_out, int out_size, void* d_ws, size_t ws_size,
                              hipStream_t stream) {
  (void)in_sizes; (void)n_in; (void)out_size; (void)ws_size;
  const float* x   = (const float*)d_in[0];
  const int*   ei  = (const int*)d_in[1];
  const float* pw1 = (const float*)d_in[2];
  const float* pb1 = (const float*)d_in[3];
  const float* pw2 = (const float*)d_in[4];
  const float* pb2 = (const float*)d_in[5];
  const float* ing = (const float*)d_in[6];
  const float* inb = (const float*)d_in[7];
  const float* swl = (const float*)d_in[8];
  const float* sbl = (const float*)d_in[9];
  const float* swr = (const float*)d_in[10];
  const float* lng = (const float*)d_in[11];
  const float* lnb = (const float*)d_in[12];
  const float* cw1 = (const float*)d_in[13];
  const float* cb1 = (const float*)d_in[14];
  const float* cw2 = (const float*)d_in[15];
  const float* cb2 = (const float*)d_in[16];

  float* out_logits = (float*)d_out;
  float* out_h = out_logits + (size_t)NN * CC;

  const size_t NNH = (size_t)NN * HH;
  u16*   hb   = (u16*)d_ws;                // 12.8 MB
  u16*   bufA = hb + NNH;                  // 12.8 MB (agg)
  u16*   wt   = bufA + NNH;                // 256 KB
  int*   cnt    = (int*)(wt + 8 * 16384);  // NN
  float* inv    = (float*)(cnt + NN);      // NN
  int*   rloc   = (int*)(inv + NN);        // NN   (block-local exclusive scan)
  int*   rpf    = rloc + NN;               // NN+1 (finalized rowptr for gather)
  int*   bsum   = rpf + NN + 1;            // 256
  int*   rankar = bsum + 256;              // EE
  u16*   colarr = (u16*)(rankar + EE);     // EE (u16 node ids)
  unsigned char* h8 = (unsigned char*)(colarr + EE);  // NN*128 bytes (fp8)

  // ---- prelude: WT1/WT2 transpose + cnt zero ----
  const int PRE_B = (2 * 16384 + NN + 255) / 256;
  k_pre<<<PRE_B, 256, 0, stream>>>(pw1, pw2, wt, cnt);

  // ---- input MLP with degree histogram + sage/cls weight-prep ridden in ----
  k_mlp_deg<<<MG + DEGB + WPB, 256, 0, stream>>>(
      x, wt + 0 * 16384, pb1, wt + 1 * 16384, pb2, ing, inb, hb, h8,
      ei, cnt, rankar, swl, swr, cw1, cw2, wt);

  // ---- CSR: block scan, then merged {finalize rpf | fill col} ----
  k_scan_block<<<SCAN_NB, 256, 0, stream>>>(cnt, rloc, bsum, inv);
  k_scanfill<<<SCAN_NB + FILLB, 256, 0, stream>>>(rloc, bsum, rpf, ei, rankar, colarr);

  // layer 0 (fp8 gather)
  k_gather8<<<(NN + 15) / 16, 256, 0, stream>>>(h8, rpf, colarr, inv, bufA);
  k_sage0<<<(NN + 127) / 128, 256, 0, stream>>>(
      bufA, hb, wt + 2 * 16384, wt + 4 * 16384, sbl, lng, lnb, hb, h8);

  // layer 1 + classifier
  k_gather8<<<(NN + 15) / 16, 256, 0, stream>>>(h8, rpf, colarr, inv, bufA);
  k_sage_cls<<<(NN + 127) / 128, 256, 0, stream>>>(
      bufA, hb, wt + 3 * 16384, wt + 5 * 16384, sbl + HH, lng + HH, lnb + HH,
      wt + 6 * 16384, cb1, wt + 7 * 16384, cb2, out_h, out_logits);
}